// Round 8
// baseline (160.504 us; speedup 1.0000x reference)
//
#include <hip/hip_runtime.h>
#include <cstddef>

#define K 64
#define D 768
#define D4 192   // D/4

__device__ __forceinline__ float d4f(float4 a, float4 b) {
  return a.x*b.x + a.y*b.y + a.z*b.z + a.w*b.w;
}
__device__ __forceinline__ float4 a4(float4 a, float4 b) {
  return make_float4(a.x+b.x, a.y+b.y, a.z+b.z, a.w+b.w);
}
__device__ __forceinline__ unsigned short f2bf(float x) {
  unsigned int u = __float_as_uint(x);
  unsigned int r = (u + 0x7FFFu + ((u >> 16) & 1u)) >> 16;
  return (unsigned short)r;
}
__device__ __forceinline__ float bflo(unsigned u) { return __uint_as_float(u << 16); }
__device__ __forceinline__ float bfhi(unsigned u) { return __uint_as_float(u & 0xFFFF0000u); }

typedef __attribute__((ext_vector_type(8)))  short bf16x8;
typedef __attribute__((ext_vector_type(16))) float f32x16;

// =====================================================================
// FAST PATH (N=32768, NC=256, C=128)
// =====================================================================
#define NCF 256
#define CF  128
#define NF  32768

// ---- K1v: pure streaming cast inputs f32 -> bf16 (no reductions) ----
__global__ __launch_bounds__(256) void k1v(
    const float* __restrict__ inputs, unsigned short* __restrict__ Vb)
{
  size_t i = ((size_t)blockIdx.x * 256 + threadIdx.x) * 4;
  float4 f = *(const float4*)(inputs + i);
  ushort4 o; o.x = f2bf(f.x); o.y = f2bf(f.y); o.z = f2bf(f.z); o.w = f2bf(f.w);
  *(ushort4*)(Vb + i) = o;
}

// ---- K1c: cast cavg to bf16 + exact ||row||^2 ----
__global__ __launch_bounds__(256) void k1c(
    const float* __restrict__ cavg, unsigned short* __restrict__ cavgb,
    float* __restrict__ cn2)
{
  int wave = blockIdx.x * 4 + (threadIdx.x >> 6);
  int l = threadIdx.x & 63;
  if (wave >= K) return;
  const float* src = cavg + (size_t)wave * D;
  unsigned short* dst = cavgb + (size_t)wave * D;
  float sq = 0.f;
#pragma unroll
  for (int t = 0; t < 3; ++t) {
    float4 v = ((const float4*)src)[t * 64 + l];
    sq += v.x*v.x + v.y*v.y + v.z*v.z + v.w*v.w;
    ushort4 o; o.x = f2bf(v.x); o.y = f2bf(v.y); o.z = f2bf(v.z); o.w = f2bf(v.w);
    ((ushort4*)dst)[t * 64 + l] = o;
  }
#pragma unroll
  for (int m = 1; m <= 32; m <<= 1) sq += __shfl_xor(sq, m);
  if (l == 0) cn2[wave] = sq;
}

// ---- K2v5: per-chunk sums GEMM from bf16 Vb, reg-prefetched slabs ----
#define LDT2 132  // Vt row stride (bf16 elems)
#define LDM  136  // Mt row stride
__global__ __launch_bounds__(256) void k2_v5(
    const unsigned short* __restrict__ Vb, const int* __restrict__ labels,
    unsigned short* __restrict__ sums, int* __restrict__ cnts_t)
{
  __shared__ unsigned short Vt[128 * LDT2];   // 33792 B
  __shared__ unsigned short Mt[64 * LDM];     // 17408 B
  const int bi = blockIdx.x;
  const int m = bi / 3, g = bi % 3;
  const int tid = threadIdx.x;
  const int w = tid >> 6, l = tid & 63;
  const int r31 = l & 31, kh = l >> 5;

  for (int e = tid; e < 64 * LDM / 2; e += 256) ((unsigned int*)Mt)[e] = 0u;
  __syncthreads();
  if (tid < 128) Mt[labels[m * 128 + tid] * LDM + tid] = 0x3F80;
  __syncthreads();
  if (g == 0 && tid < 64) {
    int c = 0;
    for (int j = 0; j < 128; ++j) c += (Mt[tid * LDM + j] != 0);
    cnts_t[tid * NCF + m] = c;
  }

  // prefetch slab 0 (128 rows x 128 cols bf16 = 8 uint4/thread)
  uint4 vreg[8];
#pragma unroll
  for (int it = 0; it < 8; ++it) {
    int flat = it * 256 + tid;
    int row = flat >> 4, c = flat & 15;
    vreg[it] = *(const uint4*)(Vb + (size_t)(m * 128 + row) * D + (g * 2) * 128 + c * 8);
  }

  for (int sl = 0; sl < 2; ++sl) {
    const int kd = g * 2 + sl;
    __syncthreads();   // prior MFMA reads of Vt done
#pragma unroll
    for (int it = 0; it < 8; ++it) {
      int flat = it * 256 + tid;
      int row = flat >> 4, c = flat & 15;
      *(uint4*)(Vt + row * LDT2 + c * 8) = vreg[it];
    }
    __syncthreads();
    if (sl == 0) {
#pragma unroll
      for (int it = 0; it < 8; ++it) {
        int flat = it * 256 + tid;
        int row = flat >> 4, c = flat & 15;
        vreg[it] = *(const uint4*)(Vb + (size_t)(m * 128 + row) * D + (g * 2 + 1) * 128 + c * 8);
      }
    }
    f32x16 acc0 = (f32x16){}, acc1 = (f32x16){};
#pragma unroll
    for (int kk = 0; kk < 8; ++kk) {
      bf16x8 a0 = *(const bf16x8*)(Mt + (r31) * LDM + kk * 16 + kh * 8);
      bf16x8 a1 = *(const bf16x8*)(Mt + (32 + r31) * LDM + kk * 16 + kh * 8);
      bf16x8 b;
#pragma unroll
      for (int r = 0; r < 8; ++r)
        b[r] = *(const short*)(Vt + (kk * 16 + kh * 8 + r) * LDT2 + w * 32 + r31);
      acc0 = __builtin_amdgcn_mfma_f32_32x32x16_bf16(a0, b, acc0, 0, 0, 0);
      acc1 = __builtin_amdgcn_mfma_f32_32x32x16_bf16(a1, b, acc1, 0, 0, 0);
    }
    unsigned short* sp = sums + (size_t)m * (K * D) + kd * 128;
#pragma unroll
    for (int q = 0; q < 16; ++q) {
      int kc = (q & 3) + 8 * (q >> 2) + 4 * kh;
      sp[(size_t)kc * D + w * 32 + r31]        = f2bf(acc0[q]);
      sp[(size_t)(32 + kc) * D + w * 32 + r31] = f2bf(acc1[q]);
    }
  }
}

// ---- K2b: exclusive scan of transposed counts ----
__global__ void k2b_scan_cnts(int* __restrict__ cnts_t, int NC)
{
  int k = threadIdx.x;
  int run = 0;
  int* p = cnts_t + k * NC;
  for (int m = 0; m < NC; ++m) { int t = p[m]; p[m] = run; run += t; }
}

// ---- K3a: level-1 exclusive scan over 16 chunks, IN PLACE on bf16 sums ----
__global__ __launch_bounds__(256) void k3a_scan_lo(
    unsigned short* __restrict__ sums, float* __restrict__ aux)
{
  const int g  = blockIdx.x / 96;
  const int cp = (blockIdx.x % 96) * 256 + threadIdx.x;  // column pair
  const int col = cp * 2;
  float run0 = 0.f, run1 = 0.f;
  for (int m = g * 16; m < g * 16 + 16; ++m) {
    size_t idx = (size_t)m * (K * D) + col;
    unsigned u = *(const unsigned*)(sums + idx);
    float t0 = bflo(u), t1 = bfhi(u);
    *(unsigned*)(sums + idx) = (unsigned)f2bf(run0) | ((unsigned)f2bf(run1) << 16);
    run0 += t0; run1 += t1;
  }
  aux[(size_t)g * (K * D) + col]     = run0;
  aux[(size_t)g * (K * D) + col + 1] = run1;
}

// ---- K3b: scan group totals (f32) ----
__global__ __launch_bounds__(256) void k3b_scan_hi(float* __restrict__ aux)
{
  int col = blockIdx.x * 256 + threadIdx.x;
  float run = 0.f;
  for (int g = 0; g < 16; ++g) {
    size_t idx = (size_t)g * (K * D) + col;
    float t = aux[idx]; aux[idx] = run; run += t;
  }
}

// ---- K4v5: fused GEMMs + epilogue; ALL staging operands reg-prefetched ----
#define LDV2 136  // bf16 row stride for 128-col tiles
#define LDD  132  // f32 dot LDS stride
__global__ __launch_bounds__(512, 4) void k4_v5(
    const unsigned short* __restrict__ Vb, const unsigned short* __restrict__ base,
    const float* __restrict__ aux, const unsigned short* __restrict__ cavgb,
    const int* __restrict__ labels, const int* __restrict__ cnts_t,
    const float* __restrict__ cn2, float* __restrict__ out)
{
  __shared__ unsigned short smem[2 * 128 * LDV2];   // Vt | Bt; later f32 dot[128][LDD]
  __shared__ float pvL[128];
  __shared__ float bn2L[64];
  __shared__ int   labL[128];
  __shared__ float chk[8][64];
  unsigned short* Vt = smem;
  unsigned short* Bt = smem + 128 * LDV2;
  const int m = blockIdx.x;
  const int g = m >> 4;
  const int tid = threadIdx.x;
  const int w = tid >> 6, l = tid & 63;
  const int r31 = l & 31, kh = l >> 5;
  const int wr = w & 3;          // output row-tile (32 rows)
  const int wt = (w >> 2) * 2;   // output col-tile base

  if (tid < 128) labL[tid] = labels[m * 128 + tid];
  if (tid < 64) bn2L[tid] = 0.f;
  __syncthreads();

  f32x16 accP[2], accS[2];
  accP[0] = (f32x16){}; accP[1] = (f32x16){};
  accS[0] = (f32x16){}; accS[1] = (f32x16){};

  // prefetch registers: V (all rows), base+aux (rows 0-63 = it 0,1),
  // cavgb (rows 64-127 = it 2,3)
  uint4 vreg[4], breg[2], creg[2];
  float4 areg[4];

#define PREF(sx) do {                                                          \
    _Pragma("unroll")                                                          \
    for (int it = 0; it < 4; ++it) {                                           \
      int flat = it * 512 + tid;                                               \
      int row = flat >> 4, c = flat & 15;                                      \
      vreg[it] = *(const uint4*)(Vb + (size_t)(m * 128 + row) * D + (sx) * 128 + c * 8); \
      if (it < 2) {                                                            \
        breg[it] = *(const uint4*)(base + ((size_t)m * K + row) * D + (sx) * 128 + c * 8); \
        const float* ap = aux + ((size_t)g * K + row) * D + (sx) * 128 + c * 8; \
        areg[it * 2]     = *(const float4*)ap;                                 \
        areg[it * 2 + 1] = *(const float4*)(ap + 4);                           \
      } else {                                                                 \
        creg[it - 2] = *(const uint4*)(cavgb + (size_t)(row - 64) * D + (sx) * 128 + c * 8); \
      }                                                                        \
    }                                                                          \
  } while (0)

  PREF(0);

  for (int s = 0; s < 6; ++s) {
    // ---- write phase: pure LDS/VALU (everything already in registers) ----
#pragma unroll
    for (int it = 0; it < 4; ++it) {
      int flat = it * 512 + tid;
      int row = flat >> 4, c = flat & 15;
      *(uint4*)(Vt + row * LDV2 + c * 8) = vreg[it];
      if (it < 2) {
        uint4 ub = breg[it];
        float4 af0 = areg[it * 2], af1 = areg[it * 2 + 1];
        float f0 = bflo(ub.x) + af0.x, f1 = bfhi(ub.x) + af0.y;
        float f2 = bflo(ub.y) + af0.z, f3 = bfhi(ub.y) + af0.w;
        float f4 = bflo(ub.z) + af1.x, f5 = bfhi(ub.z) + af1.y;
        float f6 = bflo(ub.w) + af1.z, f7 = bfhi(ub.w) + af1.w;
        float sq = f0*f0 + f1*f1 + f2*f2 + f3*f3 + f4*f4 + f5*f5 + f6*f6 + f7*f7;
        sq += __shfl_xor(sq, 1); sq += __shfl_xor(sq, 2);
        sq += __shfl_xor(sq, 4); sq += __shfl_xor(sq, 8);
        if ((l & 15) == 0) atomicAdd(&bn2L[row], sq);
        uint4 u;
        u.x = (unsigned)f2bf(f0) | ((unsigned)f2bf(f1) << 16);
        u.y = (unsigned)f2bf(f2) | ((unsigned)f2bf(f3) << 16);
        u.z = (unsigned)f2bf(f4) | ((unsigned)f2bf(f5) << 16);
        u.w = (unsigned)f2bf(f6) | ((unsigned)f2bf(f7) << 16);
        *(uint4*)(Bt + row * LDV2 + c * 8) = u;
      } else {
        *(uint4*)(Bt + row * LDV2 + c * 8) = creg[it - 2];
      }
    }
    __syncthreads();
    // ---- issue next-slab loads; they land under the MFMAs below ----
    if (s < 5) PREF(s + 1);
    // ---- MFMA on this slab ----
#pragma unroll
    for (int kk = 0; kk < 8; ++kk) {
      bf16x8 av = *(const bf16x8*)(Vt + (32 * wr + r31) * LDV2 + kk * 16 + kh * 8);
#pragma unroll
      for (int ti = 0; ti < 2; ++ti) {
        int t = wt + ti;
        bf16x8 bB = *(const bf16x8*)(Bt + (32 * t + r31) * LDV2 + kk * 16 + kh * 8);
        accP[ti] = __builtin_amdgcn_mfma_f32_32x32x16_bf16(av, bB, accP[ti], 0, 0, 0);
        bf16x8 bV = *(const bf16x8*)(Vt + (32 * t + r31) * LDV2 + kk * 16 + kh * 8);
        accS[ti] = __builtin_amdgcn_mfma_f32_32x32x16_bf16(av, bV, accS[ti], 0, 0, 0);
      }
    }
    __syncthreads();
  }
#undef PREF

  // ---- pv from Gram diagonal: S[i][i] = ||v_bf16,i||^2 (before masking) ----
  {
    int ti_diag = (w == 0 || w == 6) ? 0 : (w == 1 || w == 7) ? 1 : -1;
    if (ti_diag >= 0 && wr == wt + ti_diag && ((r31 >> 2) & 1) == kh) {
      int q = (r31 & 3) + 4 * (r31 >> 3);
      pvL[32 * wr + r31] = accS[ti_diag][q];
    }
  }

  // ---- masked S -> bf16 into Vt region; one-hot Mt into Bt region ----
#pragma unroll
  for (int ti = 0; ti < 2; ++ti)
#pragma unroll
    for (int q = 0; q < 16; ++q) {
      int i = 32 * wr + (q & 3) + 8 * (q >> 2) + 4 * kh;
      int j = 32 * (wt + ti) + r31;
      Vt[i * LDV2 + j] = (j < i) ? f2bf(accS[ti][q]) : (unsigned short)0;
    }
  {
    int j = tid & 127;
    int lab = labL[j];
    int kb = (tid >> 7) * 16;
#pragma unroll
    for (int kk = 0; kk < 16; ++kk) {
      int k = kb + kk;
      Bt[k * LDV2 + j] = (lab == k) ? (unsigned short)0x3F80 : (unsigned short)0;
    }
  }
  __syncthreads();

  // ---- corr = tril_strict(S) @ onehot, into accP (class cols, waves 0-3) ----
  if (w < 4) {
#pragma unroll
    for (int kk = 0; kk < 8; ++kk) {
      bf16x8 aS = *(const bf16x8*)(Vt + (32 * wr + r31) * LDV2 + kk * 16 + kh * 8);
#pragma unroll
      for (int ti = 0; ti < 2; ++ti) {
        bf16x8 bM = *(const bf16x8*)(Bt + (32 * ti + r31) * LDV2 + kk * 16 + kh * 8);
        accP[ti] = __builtin_amdgcn_mfma_f32_32x32x16_bf16(aS, bM, accP[ti], 0, 0, 0);
      }
    }
  }
  __syncthreads();

  // ---- dot matrix -> LDS (overwrites tiles) ----
  float* dotL = (float*)smem;
#pragma unroll
  for (int ti = 0; ti < 2; ++ti)
#pragma unroll
    for (int q = 0; q < 16; ++q) {
      int i = 32 * wr + (q & 3) + 8 * (q >> 2) + 4 * kh;
      int col = 32 * (wt + ti) + r31;
      dotL[i * LDD + col] = accP[ti][q];
    }
  __syncthreads();

  // ---- wave 0: norm-recurrence checkpoints every 16 rows ----
  if (w == 0) {
    int k = l;
    bool seen = cnts_t[k * NCF + m] > 0;
    float n = seen ? bn2L[k] : 0.f;
    for (int seg = 0; seg < 8; ++seg) {
      chk[seg][k] = seen ? n : -1.f;
      if (seg == 7) break;
      for (int j = seg * 16; j < seg * 16 + 16; ++j) {
        float dS = dotL[j * LDD + k];
        float pvj = pvL[j];
        if (labL[j] == k) {
          n = seen ? (n + 2.f * dS + pvj) : pvj;
          seen = true;
        }
      }
    }
  }
  __syncthreads();

  // ---- all 8 waves: emit 16-row segment from checkpoint ----
  {
    int k = l;
    float st = chk[w][k];
    bool seen = st >= 0.f;
    float n = seen ? st : 0.f;
    float cnk = cn2[k];
    int jb = w * 16;
    for (int j = jb; j < jb + 16; ++j) {
      float dS = dotL[j * LDD + k];
      float dC = dotL[j * LDD + 64 + k];
      float pvj = pvL[j];
      int lab = labL[j];
      float val = seen ? dS : dC;
      float nn  = seen ? n : cnk;
      out[(size_t)(m * 128 + j) * K + k] = val * rsqrtf(fmaxf(nn * pvj, 1e-30f));
      if (lab == k) {
        n = seen ? (n + 2.f * dS + pvj) : pvj;
        seen = true;
      }
    }
  }
}

// =====================================================================
// FALLBACK PATH — round-1 pipeline, verbatim (known-correct)
// =====================================================================
__global__ __launch_bounds__(256) void ph1_chunk_sums(
    const float* __restrict__ inputs, const int* __restrict__ labels,
    float* __restrict__ sums, int* __restrict__ cnts, int NC, int C)
{
  __shared__ float acc[4 * K * 64];
  __shared__ int   hist[4 * K];
  const int bi    = blockIdx.x;
  const int chunk = bi / 12, slice = bi % 12;
  const int w = threadIdx.x >> 6, l = threadIdx.x & 63;

  for (int e = threadIdx.x; e < 4 * K * 64; e += 256) acc[e] = 0.f;
  hist[threadIdx.x] = 0;
  __syncthreads();

  const int C4 = C >> 2;
  const long long rbase = (long long)chunk * C + (long long)w * C4;
  float* accw = acc + w * (K * 64);
  for (int j = 0; j < C4; ++j) {
    long long r = rbase + j;
    int lab = labels[r];
    float v = inputs[r * D + slice * 64 + l];
    accw[lab * 64 + l] += v;
    if (slice == 0 && l == 0) hist[w * K + lab]++;
  }
  __syncthreads();

  float* sp = sums + (long long)chunk * (K * D) + slice * 64;
  for (int e = threadIdx.x; e < K * 64; e += 256) {
    int k = e >> 6, dl = e & 63;
    float s = acc[0*K*64 + e] + acc[1*K*64 + e] + acc[2*K*64 + e] + acc[3*K*64 + e];
    sp[k * D + dl] = s;
  }
  if (slice == 0 && threadIdx.x < K) {
    cnts[chunk * K + threadIdx.x] =
        hist[0*K + threadIdx.x] + hist[1*K + threadIdx.x] +
        hist[2*K + threadIdx.x] + hist[3*K + threadIdx.x];
  }
}

__global__ __launch_bounds__(256) void ph2a_scan_sums(float* __restrict__ sums, int NC)
{
  const int tid = blockIdx.x * 256 + threadIdx.x;
  float run = 0.f;
  for (int m = 0; m < NC; ++m) {
    long long idx = (long long)m * (K * D) + tid;
    float t = sums[idx];
    sums[idx] = run;
    run += t;
  }
}

__global__ void ph2b_scan_cnts(int* __restrict__ cnts, int NC)
{
  const int k = threadIdx.x;
  int run = 0;
  for (int m = 0; m < NC; ++m) {
    int t = cnts[m * K + k];
    cnts[m * K + k] = run;
    run += t;
  }
}

__global__ __launch_bounds__(256, 4) void ph3_scan(
    const float* __restrict__ inputs, const int* __restrict__ labels,
    const float* __restrict__ cavg, const float* __restrict__ base,
    const int* __restrict__ cnts, float* __restrict__ out, int NC, int C)
{
  const int bi = blockIdx.x;
  int chunk, quad;
  if (NC >= 8) {
    int xcd = bi & 7, slot = bi >> 3;
    chunk = xcd * (NC >> 3) + (slot >> 2);
    quad  = slot & 3;
  } else {
    chunk = bi >> 2; quad = bi & 3;
  }
  const int w = threadIdx.x >> 6, l = threadIdx.x & 63;
  const int k0 = (quad * 4 + w) * 4;

  const int cb = chunk * K + k0;
  bool vg0 = (cnts[cb+0] == 0), vg1 = (cnts[cb+1] == 0);
  bool vg2 = (cnts[cb+2] == 0), vg3 = (cnts[cb+3] == 0);

  const float4* bp = (const float4*)base + (long long)chunk * (K * D4);
  const float4* cp = (const float4*)cavg;

  float4 A0[3], A1[3], A2[3], A3[3];
#pragma unroll
  for (int t = 0; t < 3; ++t) {
    int o = t * 64 + l;
    A0[t] = vg0 ? cp[(k0+0)*D4 + o] : bp[(k0+0)*D4 + o];
    A1[t] = vg1 ? cp[(k0+1)*D4 + o] : bp[(k0+1)*D4 + o];
    A2[t] = vg2 ? cp[(k0+2)*D4 + o] : bp[(k0+2)*D4 + o];
    A3[t] = vg3 ? cp[(k0+3)*D4 + o] : bp[(k0+3)*D4 + o];
  }
  float n0 = 0.f, n1 = 0.f, n2 = 0.f, n3 = 0.f;
#pragma unroll
  for (int t = 0; t < 3; ++t) {
    n0 += d4f(A0[t], A0[t]); n1 += d4f(A1[t], A1[t]);
    n2 += d4f(A2[t], A2[t]); n3 += d4f(A3[t], A3[t]);
  }
#pragma unroll
  for (int m = 1; m <= 32; m <<= 1) {
    n0 += __shfl_xor(n0, m); n1 += __shfl_xor(n1, m);
    n2 += __shfl_xor(n2, m); n3 += __shfl_xor(n3, m);
  }

  const long long ibase = (long long)chunk * C;
  for (int j = 0; j < C; ++j) {
    const long long i = ibase + j;
    const int lab = labels[i];
    const float4* vp = (const float4*)inputs + i * D4;
    float4 v0 = vp[l], v1 = vp[64 + l], v2 = vp[128 + l];

    float p0 = d4f(A0[0], v0) + d4f(A0[1], v1) + d4f(A0[2], v2);
    float p1 = d4f(A1[0], v0) + d4f(A1[1], v1) + d4f(A1[2], v2);
    float p2 = d4f(A2[0], v0) + d4f(A2[1], v1) + d4f(A2[2], v2);
    float p3 = d4f(A3[0], v0) + d4f(A3[1], v1) + d4f(A3[2], v2);
    float pv = d4f(v0, v0) + d4f(v1, v1) + d4f(v2, v2);
#pragma unroll
    for (int m = 1; m <= 32; m <<= 1) {
      p0 += __shfl_xor(p0, m); p1 += __shfl_xor(p1, m);
      p2 += __shfl_xor(p2, m); p3 += __shfl_xor(p3, m);
      pv += __shfl_xor(pv, m);
    }
    if (l < 4) {
      float ps = (l == 0) ? p0 : (l == 1) ? p1 : (l == 2) ? p2 : p3;
      float ns = (l == 0) ? n0 : (l == 1) ? n1 : (l == 2) ? n2 : n3;
      out[i * K + k0 + l] = ps * rsqrtf(fmaxf(ns * pv, 1e-30f));
    }
#define UPD(idx) do { \
      if (vg##idx) { A##idx[0]=v0; A##idx[1]=v1; A##idx[2]=v2; n##idx = pv; vg##idx = false; } \
      else { A##idx[0]=a4(A##idx[0],v0); A##idx[1]=a4(A##idx[1],v1); A##idx[2]=a4(A##idx[2],v2); \
             n##idx += 2.f * p##idx + pv; } } while (0)
    if      (lab == k0 + 0) UPD(0);
    else if (lab == k0 + 1) UPD(1);
    else if (lab == k0 + 2) UPD(2);
    else if (lab == k0 + 3) UPD(3);
#undef UPD
  }
}

// =====================================================================
extern "C" void kernel_launch(void* const* d_in, const int* in_sizes, int n_in,
                              void* d_out, int out_size, void* d_ws, size_t ws_size,
                              hipStream_t stream)
{
  const float* inputs = (const float*)d_in[0];
  const int*   labels = (const int*)d_in[1];
  const float* cavg   = (const float*)d_in[2];
  float* out = (float*)d_out;
  const int N = in_sizes[1];

  const size_t szVb    = (size_t)NF * D * 2;      // 50.3 MB
  const size_t szSums  = (size_t)NCF * K * D * 2; // 25.2 MB (bf16, scanned in place)
  const size_t szAux   = (size_t)16 * K * D * 4;  // 3.1 MB
  const size_t szCnt   = (size_t)K * NCF * 4;
  const size_t szCavgb = (size_t)K * D * 2;
  const size_t szCn2   = (size_t)K * 4;
  size_t need = szVb + szSums + szAux + szCnt + szCavgb + szCn2 + 8 * 256;

  if (N == NF && in_sizes[2] == K * D && ws_size >= need) {
    char* p = (char*)d_ws;
    auto take = [&](size_t b) { char* r = p; p += (b + 255) & ~(size_t)255; return r; };
    unsigned short* Vb    = (unsigned short*)take(szVb);
    unsigned short* sums  = (unsigned short*)take(szSums);
    float*          aux   = (float*)take(szAux);
    int*            cnts  = (int*)take(szCnt);
    unsigned short* cavgb = (unsigned short*)take(szCavgb);
    float*          cn2   = (float*)take(szCn2);

    hipLaunchKernelGGL(k1v, dim3((NF * D) / 1024), dim3(256), 0, stream, inputs, Vb);
    hipLaunchKernelGGL(k1c, dim3(16), dim3(256), 0, stream, cavg, cavgb, cn2);
    hipLaunchKernelGGL(k2_v5, dim3(NCF * 3), dim3(256), 0, stream,
                       Vb, labels, sums, cnts);
    hipLaunchKernelGGL(k2b_scan_cnts, dim3(1), dim3(K), 0, stream, cnts, NCF);
    hipLaunchKernelGGL(k3a_scan_lo, dim3(16 * 96), dim3(256), 0, stream, sums, aux);
    hipLaunchKernelGGL(k3b_scan_hi, dim3(192), dim3(256), 0, stream, aux);
    hipLaunchKernelGGL(k4_v5, dim3(NCF), dim3(512), 0, stream,
                       Vb, sums, aux, cavgb, labels, cnts, cn2, out);
    return;
  }

  // ---------------- fallback: round-1 pipeline ----------------
  int NC = 256;
  while (NC > 1) {
    size_t nd = (size_t)NC * K * D * 4 + (size_t)NC * K * 4;
    if (nd <= ws_size && (N % (NC * 4)) == 0) break;
    NC >>= 1;
  }
  const int C = N / NC;
  float* d_sums = (float*)d_ws;
  int*   d_cnts = (int*)((char*)d_ws + (size_t)NC * K * D * 4);

  hipLaunchKernelGGL(ph1_chunk_sums, dim3(NC * 12), dim3(256), 0, stream,
                     inputs, labels, d_sums, d_cnts, NC, C);
  hipLaunchKernelGGL(ph2a_scan_sums, dim3((K * D) / 256), dim3(256), 0, stream,
                     d_sums, NC);
  hipLaunchKernelGGL(ph2b_scan_cnts, dim3(1), dim3(64), 0, stream,
                     d_cnts, NC);
  hipLaunchKernelGGL(ph3_scan, dim3(NC * 4), dim3(256), 0, stream,
                     inputs, labels, cavg, d_sums, d_cnts, out, NC, C);
}

// Round 9
// 144.356 us; speedup vs baseline: 1.1119x; 1.1119x over previous
//
#include <hip/hip_runtime.h>
#include <cstddef>

#define K 64
#define D 768
#define D4 192   // D/4

__device__ __forceinline__ float d4f(float4 a, float4 b) {
  return a.x*b.x + a.y*b.y + a.z*b.z + a.w*b.w;
}
__device__ __forceinline__ float4 a4(float4 a, float4 b) {
  return make_float4(a.x+b.x, a.y+b.y, a.z+b.z, a.w+b.w);
}
__device__ __forceinline__ unsigned short f2bf(float x) {
  unsigned int u = __float_as_uint(x);
  unsigned int r = (u + 0x7FFFu + ((u >> 16) & 1u)) >> 16;
  return (unsigned short)r;
}
__device__ __forceinline__ float bflo(unsigned u) { return __uint_as_float(u << 16); }
__device__ __forceinline__ float bfhi(unsigned u) { return __uint_as_float(u & 0xFFFF0000u); }

typedef __attribute__((ext_vector_type(8)))  short bf16x8;
typedef __attribute__((ext_vector_type(16))) float f32x16;

// =====================================================================
// FAST PATH (N=32768, NC=256, C=128)
// =====================================================================
#define NCF 256
#define CF  128
#define NF  32768

// ---- K1v: pure streaming cast inputs f32 -> bf16 ----
__global__ __launch_bounds__(256) void k1v(
    const float* __restrict__ inputs, unsigned short* __restrict__ Vb)
{
  size_t i = ((size_t)blockIdx.x * 256 + threadIdx.x) * 4;
  float4 f = *(const float4*)(inputs + i);
  ushort4 o; o.x = f2bf(f.x); o.y = f2bf(f.y); o.z = f2bf(f.z); o.w = f2bf(f.w);
  *(ushort4*)(Vb + i) = o;
}

// ---- K1c: cast cavg to bf16 + exact ||row||^2 ----
__global__ __launch_bounds__(256) void k1c(
    const float* __restrict__ cavg, unsigned short* __restrict__ cavgb,
    float* __restrict__ cn2)
{
  int wave = blockIdx.x * 4 + (threadIdx.x >> 6);
  int l = threadIdx.x & 63;
  if (wave >= K) return;
  const float* src = cavg + (size_t)wave * D;
  unsigned short* dst = cavgb + (size_t)wave * D;
  float sq = 0.f;
#pragma unroll
  for (int t = 0; t < 3; ++t) {
    float4 v = ((const float4*)src)[t * 64 + l];
    sq += v.x*v.x + v.y*v.y + v.z*v.z + v.w*v.w;
    ushort4 o; o.x = f2bf(v.x); o.y = f2bf(v.y); o.z = f2bf(v.z); o.w = f2bf(v.w);
    ((ushort4*)dst)[t * 64 + l] = o;
  }
#pragma unroll
  for (int m = 1; m <= 32; m <<= 1) sq += __shfl_xor(sq, m);
  if (l == 0) cn2[wave] = sq;
}

// ---- K2v6: per-chunk sums GEMM, ONE slab per block (grid NCF*6, 3 blk/CU) ----
#define LDT2 132  // Vt row stride (bf16 elems)
#define LDM  136  // Mt row stride
__global__ __launch_bounds__(256) void k2_v6(
    const unsigned short* __restrict__ Vb, const int* __restrict__ labels,
    unsigned short* __restrict__ sums, int* __restrict__ cnts_t)
{
  __shared__ unsigned short Vt[128 * LDT2];   // 33792 B
  __shared__ unsigned short Mt[64 * LDM];     // 17408 B  -> 51200 B total
  const int bi = blockIdx.x;
  const int m = bi / 6, g = bi % 6;           // g = 128-col slab index
  const int tid = threadIdx.x;
  const int w = tid >> 6, l = tid & 63;
  const int r31 = l & 31, kh = l >> 5;

  // issue V-slab loads first; latency hides under Mt build
  uint4 vreg[8];
#pragma unroll
  for (int it = 0; it < 8; ++it) {
    int flat = it * 256 + tid;
    int row = flat >> 4, c = flat & 15;
    vreg[it] = *(const uint4*)(Vb + (size_t)(m * 128 + row) * D + g * 128 + c * 8);
  }

  for (int e = tid; e < 64 * LDM / 2; e += 256) ((unsigned int*)Mt)[e] = 0u;
  __syncthreads();
  if (tid < 128) Mt[labels[m * 128 + tid] * LDM + tid] = 0x3F80;
  __syncthreads();
  if (g == 0 && tid < 64) {
    int c = 0;
    for (int j = 0; j < 128; ++j) c += (Mt[tid * LDM + j] != 0);
    cnts_t[tid * NCF + m] = c;
  }

#pragma unroll
  for (int it = 0; it < 8; ++it) {
    int flat = it * 256 + tid;
    int row = flat >> 4, c = flat & 15;
    *(uint4*)(Vt + row * LDT2 + c * 8) = vreg[it];
  }
  __syncthreads();

  f32x16 acc0 = (f32x16){}, acc1 = (f32x16){};
#pragma unroll
  for (int kk = 0; kk < 8; ++kk) {
    bf16x8 a0 = *(const bf16x8*)(Mt + (r31) * LDM + kk * 16 + kh * 8);
    bf16x8 a1 = *(const bf16x8*)(Mt + (32 + r31) * LDM + kk * 16 + kh * 8);
    bf16x8 b;
#pragma unroll
    for (int r = 0; r < 8; ++r)
      b[r] = *(const short*)(Vt + (kk * 16 + kh * 8 + r) * LDT2 + w * 32 + r31);
    acc0 = __builtin_amdgcn_mfma_f32_32x32x16_bf16(a0, b, acc0, 0, 0, 0);
    acc1 = __builtin_amdgcn_mfma_f32_32x32x16_bf16(a1, b, acc1, 0, 0, 0);
  }
  unsigned short* sp = sums + (size_t)m * (K * D) + g * 128;
#pragma unroll
  for (int q = 0; q < 16; ++q) {
    int kc = (q & 3) + 8 * (q >> 2) + 4 * kh;
    sp[(size_t)kc * D + w * 32 + r31]        = f2bf(acc0[q]);
    sp[(size_t)(32 + kc) * D + w * 32 + r31] = f2bf(acc1[q]);
  }
}

// ---- K2b: exclusive scan of transposed counts ----
__global__ void k2b_scan_cnts(int* __restrict__ cnts_t, int NC)
{
  int k = threadIdx.x;
  int run = 0;
  int* p = cnts_t + k * NC;
  for (int m = 0; m < NC; ++m) { int t = p[m]; p[m] = run; run += t; }
}

// ---- K3a: level-1 exclusive scan over 16 chunks, IN PLACE on bf16 sums ----
__global__ __launch_bounds__(256) void k3a_scan_lo(
    unsigned short* __restrict__ sums, float* __restrict__ aux)
{
  const int g  = blockIdx.x / 96;
  const int cp = (blockIdx.x % 96) * 256 + threadIdx.x;  // column pair
  const int col = cp * 2;
  float run0 = 0.f, run1 = 0.f;
  for (int m = g * 16; m < g * 16 + 16; ++m) {
    size_t idx = (size_t)m * (K * D) + col;
    unsigned u = *(const unsigned*)(sums + idx);
    float t0 = bflo(u), t1 = bfhi(u);
    *(unsigned*)(sums + idx) = (unsigned)f2bf(run0) | ((unsigned)f2bf(run1) << 16);
    run0 += t0; run1 += t1;
  }
  aux[(size_t)g * (K * D) + col]     = run0;
  aux[(size_t)g * (K * D) + col + 1] = run1;
}

// ---- K3b: scan group totals (f32) ----
__global__ __launch_bounds__(256) void k3b_scan_hi(float* __restrict__ aux)
{
  int col = blockIdx.x * 256 + threadIdx.x;
  float run = 0.f;
  for (int g = 0; g < 16; ++g) {
    size_t idx = (size_t)g * (K * D) + col;
    float t = aux[idx]; aux[idx] = run; run += t;
  }
}

// ---- K4v6: fused GEMMs + epilogue; 1024 threads, 16 waves x 1 tile each ----
#define LDV2 136  // bf16 row stride for 128-col tiles
#define LDD  132  // f32 dot LDS stride
__global__ __launch_bounds__(1024, 4) void k4_v6(
    const unsigned short* __restrict__ Vb, const unsigned short* __restrict__ base,
    const float* __restrict__ aux, const unsigned short* __restrict__ cavgb,
    const int* __restrict__ labels, const int* __restrict__ cnts_t,
    const float* __restrict__ cn2, float* __restrict__ out)
{
  __shared__ unsigned short smem[2 * 128 * LDV2];   // Vt | Bt; later f32 dot[128][LDD]
  __shared__ float pvL[128];
  __shared__ float bn2L[64];
  __shared__ int   labL[128];
  __shared__ float chk[16][64];
  unsigned short* Vt = smem;
  unsigned short* Bt = smem + 128 * LDV2;
  const int m = blockIdx.x;
  const int g = m >> 4;
  const int tid = threadIdx.x;
  const int w = tid >> 6, l = tid & 63;
  const int r31 = l & 31, kh = l >> 5;
  const int wr = w & 3;    // output row-tile (32 rows)
  const int wc = w >> 2;   // output col-tile (32 cols)

  if (tid < 128) labL[tid] = labels[m * 128 + tid];
  if (tid < 64) bn2L[tid] = 0.f;
  __syncthreads();

  f32x16 accP = (f32x16){}, accS = (f32x16){};

  // prefetch: per thread 2 V uint4; rows 0-63 (it=0): base uint4 + aux 2xfloat4;
  // rows 64-127 (it=1): cavg uint4.
  uint4 vreg[2], breg, creg;
  float4 areg[2];

#define PREF(sx) do {                                                          \
    _Pragma("unroll")                                                          \
    for (int it = 0; it < 2; ++it) {                                           \
      int flat = it * 1024 + tid;                                              \
      int row = flat >> 4, c = flat & 15;                                      \
      vreg[it] = *(const uint4*)(Vb + (size_t)(m * 128 + row) * D + (sx) * 128 + c * 8); \
      if (it == 0) {                                                           \
        breg = *(const uint4*)(base + ((size_t)m * K + row) * D + (sx) * 128 + c * 8); \
        const float* ap = aux + ((size_t)g * K + row) * D + (sx) * 128 + c * 8; \
        areg[0] = *(const float4*)ap;                                          \
        areg[1] = *(const float4*)(ap + 4);                                    \
      } else {                                                                 \
        creg = *(const uint4*)(cavgb + (size_t)(row - 64) * D + (sx) * 128 + c * 8); \
      }                                                                        \
    }                                                                          \
  } while (0)

  PREF(0);

  for (int s = 0; s < 6; ++s) {
    // ---- write phase: pure LDS/VALU ----
#pragma unroll
    for (int it = 0; it < 2; ++it) {
      int flat = it * 1024 + tid;
      int row = flat >> 4, c = flat & 15;
      *(uint4*)(Vt + row * LDV2 + c * 8) = vreg[it];
      if (it == 0) {
        uint4 ub = breg;
        float4 af0 = areg[0], af1 = areg[1];
        float f0 = bflo(ub.x) + af0.x, f1 = bfhi(ub.x) + af0.y;
        float f2 = bflo(ub.y) + af0.z, f3 = bfhi(ub.y) + af0.w;
        float f4 = bflo(ub.z) + af1.x, f5 = bfhi(ub.z) + af1.y;
        float f6 = bflo(ub.w) + af1.z, f7 = bfhi(ub.w) + af1.w;
        float sq = f0*f0 + f1*f1 + f2*f2 + f3*f3 + f4*f4 + f5*f5 + f6*f6 + f7*f7;
        sq += __shfl_xor(sq, 1); sq += __shfl_xor(sq, 2);
        sq += __shfl_xor(sq, 4); sq += __shfl_xor(sq, 8);
        if ((l & 15) == 0) atomicAdd(&bn2L[row], sq);
        uint4 u;
        u.x = (unsigned)f2bf(f0) | ((unsigned)f2bf(f1) << 16);
        u.y = (unsigned)f2bf(f2) | ((unsigned)f2bf(f3) << 16);
        u.z = (unsigned)f2bf(f4) | ((unsigned)f2bf(f5) << 16);
        u.w = (unsigned)f2bf(f6) | ((unsigned)f2bf(f7) << 16);
        *(uint4*)(Bt + row * LDV2 + c * 8) = u;
      } else {
        *(uint4*)(Bt + row * LDV2 + c * 8) = creg;
      }
    }
    __syncthreads();
    if (s < 5) PREF(s + 1);
    // ---- MFMA: one (wr,wc) tile per wave ----
#pragma unroll
    for (int kk = 0; kk < 8; ++kk) {
      bf16x8 av = *(const bf16x8*)(Vt + (32 * wr + r31) * LDV2 + kk * 16 + kh * 8);
      bf16x8 bB = *(const bf16x8*)(Bt + (32 * wc + r31) * LDV2 + kk * 16 + kh * 8);
      accP = __builtin_amdgcn_mfma_f32_32x32x16_bf16(av, bB, accP, 0, 0, 0);
      bf16x8 bV = *(const bf16x8*)(Vt + (32 * wc + r31) * LDV2 + kk * 16 + kh * 8);
      accS = __builtin_amdgcn_mfma_f32_32x32x16_bf16(av, bV, accS, 0, 0, 0);
    }
    __syncthreads();
  }
#undef PREF

  // ---- pv from Gram diagonal (diag tiles: wr==wc) ----
  if (wr == wc && ((r31 >> 2) & 1) == kh) {
    int q = (r31 & 3) + 4 * (r31 >> 3);
    pvL[32 * wr + r31] = accS[q];
  }

  // ---- masked S -> bf16 into Vt region; one-hot Mt into Bt region ----
#pragma unroll
  for (int q = 0; q < 16; ++q) {
    int i = 32 * wr + (q & 3) + 8 * (q >> 2) + 4 * kh;
    int j = 32 * wc + r31;
    Vt[i * LDV2 + j] = (j < i) ? f2bf(accS[q]) : (unsigned short)0;
  }
  {
    int j = tid & 127;
    int lab = labL[j];
    int kb = (tid >> 7) * 8;
#pragma unroll
    for (int kk = 0; kk < 8; ++kk) {
      int k = kb + kk;
      Bt[k * LDV2 + j] = (lab == k) ? (unsigned short)0x3F80 : (unsigned short)0;
    }
  }
  __syncthreads();

  // ---- corr = tril_strict(S) @ onehot; waves 0-7 own the class-col tiles ----
  if (w < 8) {
#pragma unroll
    for (int kk = 0; kk < 8; ++kk) {
      bf16x8 aS = *(const bf16x8*)(Vt + (32 * wr + r31) * LDV2 + kk * 16 + kh * 8);
      bf16x8 bM = *(const bf16x8*)(Bt + (32 * wc + r31) * LDV2 + kk * 16 + kh * 8);
      accP = __builtin_amdgcn_mfma_f32_32x32x16_bf16(aS, bM, accP, 0, 0, 0);
    }
  }
  __syncthreads();

  // ---- dot matrix -> LDS (overwrites tiles) ----
  float* dotL = (float*)smem;
#pragma unroll
  for (int q = 0; q < 16; ++q) {
    int i = 32 * wr + (q & 3) + 8 * (q >> 2) + 4 * kh;
    dotL[i * LDD + 32 * wc + r31] = accP[q];
  }
  __syncthreads();

  // ---- wave 0: norm-recurrence checkpoints every 8 rows ----
  if (w == 0) {
    int k = l;
    bool seen = cnts_t[k * NCF + m] > 0;
    float n = seen ? bn2L[k] : 0.f;
    for (int seg = 0; seg < 16; ++seg) {
      chk[seg][k] = seen ? n : -1.f;
      if (seg == 15) break;
      for (int j = seg * 8; j < seg * 8 + 8; ++j) {
        float dS = dotL[j * LDD + k];
        float pvj = pvL[j];
        if (labL[j] == k) {
          n = seen ? (n + 2.f * dS + pvj) : pvj;
          seen = true;
        }
      }
    }
  }
  __syncthreads();

  // ---- all 16 waves: emit 8-row segment from checkpoint ----
  {
    int k = l;
    float st = chk[w][k];
    bool seen = st >= 0.f;
    float n = seen ? st : 0.f;
    float cnk = cn2[k];
    int jb = w * 8;
    for (int j = jb; j < jb + 8; ++j) {
      float dS = dotL[j * LDD + k];
      float dC = dotL[j * LDD + 64 + k];
      float pvj = pvL[j];
      int lab = labL[j];
      float val = seen ? dS : dC;
      float nn  = seen ? n : cnk;
      out[(size_t)(m * 128 + j) * K + k] = val * rsqrtf(fmaxf(nn * pvj, 1e-30f));
      if (lab == k) {
        n = seen ? (n + 2.f * dS + pvj) : pvj;
        seen = true;
      }
    }
  }
}

// =====================================================================
// FALLBACK PATH — round-1 pipeline, verbatim (known-correct)
// =====================================================================
__global__ __launch_bounds__(256) void ph1_chunk_sums(
    const float* __restrict__ inputs, const int* __restrict__ labels,
    float* __restrict__ sums, int* __restrict__ cnts, int NC, int C)
{
  __shared__ float acc[4 * K * 64];
  __shared__ int   hist[4 * K];
  const int bi    = blockIdx.x;
  const int chunk = bi / 12, slice = bi % 12;
  const int w = threadIdx.x >> 6, l = threadIdx.x & 63;

  for (int e = threadIdx.x; e < 4 * K * 64; e += 256) acc[e] = 0.f;
  hist[threadIdx.x] = 0;
  __syncthreads();

  const int C4 = C >> 2;
  const long long rbase = (long long)chunk * C + (long long)w * C4;
  float* accw = acc + w * (K * 64);
  for (int j = 0; j < C4; ++j) {
    long long r = rbase + j;
    int lab = labels[r];
    float v = inputs[r * D + slice * 64 + l];
    accw[lab * 64 + l] += v;
    if (slice == 0 && l == 0) hist[w * K + lab]++;
  }
  __syncthreads();

  float* sp = sums + (long long)chunk * (K * D) + slice * 64;
  for (int e = threadIdx.x; e < K * 64; e += 256) {
    int k = e >> 6, dl = e & 63;
    float s = acc[0*K*64 + e] + acc[1*K*64 + e] + acc[2*K*64 + e] + acc[3*K*64 + e];
    sp[k * D + dl] = s;
  }
  if (slice == 0 && threadIdx.x < K) {
    cnts[chunk * K + threadIdx.x] =
        hist[0*K + threadIdx.x] + hist[1*K + threadIdx.x] +
        hist[2*K + threadIdx.x] + hist[3*K + threadIdx.x];
  }
}

__global__ __launch_bounds__(256) void ph2a_scan_sums(float* __restrict__ sums, int NC)
{
  const int tid = blockIdx.x * 256 + threadIdx.x;
  float run = 0.f;
  for (int m = 0; m < NC; ++m) {
    long long idx = (long long)m * (K * D) + tid;
    float t = sums[idx];
    sums[idx] = run;
    run += t;
  }
}

__global__ void ph2b_scan_cnts(int* __restrict__ cnts, int NC)
{
  const int k = threadIdx.x;
  int run = 0;
  for (int m = 0; m < NC; ++m) {
    int t = cnts[m * K + k];
    cnts[m * K + k] = run;
    run += t;
  }
}

__global__ __launch_bounds__(256, 4) void ph3_scan(
    const float* __restrict__ inputs, const int* __restrict__ labels,
    const float* __restrict__ cavg, const float* __restrict__ base,
    const int* __restrict__ cnts, float* __restrict__ out, int NC, int C)
{
  const int bi = blockIdx.x;
  int chunk, quad;
  if (NC >= 8) {
    int xcd = bi & 7, slot = bi >> 3;
    chunk = xcd * (NC >> 3) + (slot >> 2);
    quad  = slot & 3;
  } else {
    chunk = bi >> 2; quad = bi & 3;
  }
  const int w = threadIdx.x >> 6, l = threadIdx.x & 63;
  const int k0 = (quad * 4 + w) * 4;

  const int cb = chunk * K + k0;
  bool vg0 = (cnts[cb+0] == 0), vg1 = (cnts[cb+1] == 0);
  bool vg2 = (cnts[cb+2] == 0), vg3 = (cnts[cb+3] == 0);

  const float4* bp = (const float4*)base + (long long)chunk * (K * D4);
  const float4* cp = (const float4*)cavg;

  float4 A0[3], A1[3], A2[3], A3[3];
#pragma unroll
  for (int t = 0; t < 3; ++t) {
    int o = t * 64 + l;
    A0[t] = vg0 ? cp[(k0+0)*D4 + o] : bp[(k0+0)*D4 + o];
    A1[t] = vg1 ? cp[(k0+1)*D4 + o] : bp[(k0+1)*D4 + o];
    A2[t] = vg2 ? cp[(k0+2)*D4 + o] : bp[(k0+2)*D4 + o];
    A3[t] = vg3 ? cp[(k0+3)*D4 + o] : bp[(k0+3)*D4 + o];
  }
  float n0 = 0.f, n1 = 0.f, n2 = 0.f, n3 = 0.f;
#pragma unroll
  for (int t = 0; t < 3; ++t) {
    n0 += d4f(A0[t], A0[t]); n1 += d4f(A1[t], A1[t]);
    n2 += d4f(A2[t], A2[t]); n3 += d4f(A3[t], A3[t]);
  }
#pragma unroll
  for (int m = 1; m <= 32; m <<= 1) {
    n0 += __shfl_xor(n0, m); n1 += __shfl_xor(n1, m);
    n2 += __shfl_xor(n2, m); n3 += __shfl_xor(n3, m);
  }

  const long long ibase = (long long)chunk * C;
  for (int j = 0; j < C; ++j) {
    const long long i = ibase + j;
    const int lab = labels[i];
    const float4* vp = (const float4*)inputs + i * D4;
    float4 v0 = vp[l], v1 = vp[64 + l], v2 = vp[128 + l];

    float p0 = d4f(A0[0], v0) + d4f(A0[1], v1) + d4f(A0[2], v2);
    float p1 = d4f(A1[0], v0) + d4f(A1[1], v1) + d4f(A1[2], v2);
    float p2 = d4f(A2[0], v0) + d4f(A2[1], v1) + d4f(A2[2], v2);
    float p3 = d4f(A3[0], v0) + d4f(A3[1], v1) + d4f(A3[2], v2);
    float pv = d4f(v0, v0) + d4f(v1, v1) + d4f(v2, v2);
#pragma unroll
    for (int m = 1; m <= 32; m <<= 1) {
      p0 += __shfl_xor(p0, m); p1 += __shfl_xor(p1, m);
      p2 += __shfl_xor(p2, m); p3 += __shfl_xor(p3, m);
      pv += __shfl_xor(pv, m);
    }
    if (l < 4) {
      float ps = (l == 0) ? p0 : (l == 1) ? p1 : (l == 2) ? p2 : p3;
      float ns = (l == 0) ? n0 : (l == 1) ? n1 : (l == 2) ? n2 : n3;
      out[i * K + k0 + l] = ps * rsqrtf(fmaxf(ns * pv, 1e-30f));
    }
#define UPD(idx) do { \
      if (vg##idx) { A##idx[0]=v0; A##idx[1]=v1; A##idx[2]=v2; n##idx = pv; vg##idx = false; } \
      else { A##idx[0]=a4(A##idx[0],v0); A##idx[1]=a4(A##idx[1],v1); A##idx[2]=a4(A##idx[2],v2); \
             n##idx += 2.f * p##idx + pv; } } while (0)
    if      (lab == k0 + 0) UPD(0);
    else if (lab == k0 + 1) UPD(1);
    else if (lab == k0 + 2) UPD(2);
    else if (lab == k0 + 3) UPD(3);
#undef UPD
  }
}

// =====================================================================
extern "C" void kernel_launch(void* const* d_in, const int* in_sizes, int n_in,
                              void* d_out, int out_size, void* d_ws, size_t ws_size,
                              hipStream_t stream)
{
  const float* inputs = (const float*)d_in[0];
  const int*   labels = (const int*)d_in[1];
  const float* cavg   = (const float*)d_in[2];
  float* out = (float*)d_out;
  const int N = in_sizes[1];

  const size_t szVb    = (size_t)NF * D * 2;      // 50.3 MB
  const size_t szSums  = (size_t)NCF * K * D * 2; // 25.2 MB (bf16, scanned in place)
  const size_t szAux   = (size_t)16 * K * D * 4;  // 3.1 MB
  const size_t szCnt   = (size_t)K * NCF * 4;
  const size_t szCavgb = (size_t)K * D * 2;
  const size_t szCn2   = (size_t)K * 4;
  size_t need = szVb + szSums + szAux + szCnt + szCavgb + szCn2 + 8 * 256;

  if (N == NF && in_sizes[2] == K * D && ws_size >= need) {
    char* p = (char*)d_ws;
    auto take = [&](size_t b) { char* r = p; p += (b + 255) & ~(size_t)255; return r; };
    unsigned short* Vb    = (unsigned short*)take(szVb);
    unsigned short* sums  = (unsigned short*)take(szSums);
    float*          aux   = (float*)take(szAux);
    int*            cnts  = (int*)take(szCnt);
    unsigned short* cavgb = (unsigned short*)take(szCavgb);
    float*          cn2   = (float*)take(szCn2);

    hipLaunchKernelGGL(k1v, dim3((NF * D) / 1024), dim3(256), 0, stream, inputs, Vb);
    hipLaunchKernelGGL(k1c, dim3(16), dim3(256), 0, stream, cavg, cavgb, cn2);
    hipLaunchKernelGGL(k2_v6, dim3(NCF * 6), dim3(256), 0, stream,
                       Vb, labels, sums, cnts);
    hipLaunchKernelGGL(k2b_scan_cnts, dim3(1), dim3(K), 0, stream, cnts, NCF);
    hipLaunchKernelGGL(k3a_scan_lo, dim3(16 * 96), dim3(256), 0, stream, sums, aux);
    hipLaunchKernelGGL(k3b_scan_hi, dim3(192), dim3(256), 0, stream, aux);
    hipLaunchKernelGGL(k4_v6, dim3(NCF), dim3(1024), 0, stream,
                       Vb, sums, aux, cavgb, labels, cnts, cn2, out);
    return;
  }

  // ---------------- fallback: round-1 pipeline ----------------
  int NC = 256;
  while (NC > 1) {
    size_t nd = (size_t)NC * K * D * 4 + (size_t)NC * K * 4;
    if (nd <= ws_size && (N % (NC * 4)) == 0) break;
    NC >>= 1;
  }
  const int C = N / NC;
  float* d_sums = (float*)d_ws;
  int*   d_cnts = (int*)((char*)d_ws + (size_t)NC * K * D * 4);

  hipLaunchKernelGGL(ph1_chunk_sums, dim3(NC * 12), dim3(256), 0, stream,
                     inputs, labels, d_sums, d_cnts, NC, C);
  hipLaunchKernelGGL(ph2a_scan_sums, dim3((K * D) / 256), dim3(256), 0, stream,
                     d_sums, NC);
  hipLaunchKernelGGL(ph2b_scan_cnts, dim3(1), dim3(64), 0, stream,
                     d_cnts, NC);
  hipLaunchKernelGGL(ph3_scan, dim3(NC * 4), dim3(256), 0, stream,
                     inputs, labels, cavg, d_sums, d_cnts, out, NC, C);
}

// Round 10
// 106.878 us; speedup vs baseline: 1.5017x; 1.3507x over previous
//
#include <hip/hip_runtime.h>
#include <cstddef>

#define K 64
#define D 768
#define D4 192   // D/4

__device__ __forceinline__ float d4f(float4 a, float4 b) {
  return a.x*b.x + a.y*b.y + a.z*b.z + a.w*b.w;
}
__device__ __forceinline__ float4 a4(float4 a, float4 b) {
  return make_float4(a.x+b.x, a.y+b.y, a.z+b.z, a.w+b.w);
}
__device__ __forceinline__ unsigned short f2bf(float x) {
  unsigned int u = __float_as_uint(x);
  unsigned int r = (u + 0x7FFFu + ((u >> 16) & 1u)) >> 16;
  return (unsigned short)r;
}
__device__ __forceinline__ float bflo(unsigned u) { return __uint_as_float(u << 16); }
__device__ __forceinline__ float bfhi(unsigned u) { return __uint_as_float(u & 0xFFFF0000u); }

typedef __attribute__((ext_vector_type(8)))  short bf16x8;
typedef __attribute__((ext_vector_type(16))) float f32x16;

// =====================================================================
// FAST PATH (N=32768, NC=256, C=128)
// =====================================================================
#define NCF 256
#define CF  128
#define NF  32768
#define NBV (NF * D / 1024)   // 24576 cast blocks

// ---- K1: streaming cast of inputs (+ cavg tail blocks with row norms) ----
__global__ __launch_bounds__(256) void k1_all(
    const float* __restrict__ inputs, const float* __restrict__ cavg,
    unsigned short* __restrict__ Vb, unsigned short* __restrict__ cavgb,
    float* __restrict__ cn2)
{
  if (blockIdx.x < NBV) {
    size_t i = ((size_t)blockIdx.x * 256 + threadIdx.x) * 4;
    float4 f = *(const float4*)(inputs + i);
    ushort4 o; o.x = f2bf(f.x); o.y = f2bf(f.y); o.z = f2bf(f.z); o.w = f2bf(f.w);
    *(ushort4*)(Vb + i) = o;
    return;
  }
  int wave = (blockIdx.x - NBV) * 4 + (threadIdx.x >> 6);
  int l = threadIdx.x & 63;
  if (wave >= K) return;
  const float* src = cavg + (size_t)wave * D;
  unsigned short* dst = cavgb + (size_t)wave * D;
  float sq = 0.f;
#pragma unroll
  for (int t = 0; t < 3; ++t) {
    float4 v = ((const float4*)src)[t * 64 + l];
    sq += v.x*v.x + v.y*v.y + v.z*v.z + v.w*v.w;
    ushort4 o; o.x = f2bf(v.x); o.y = f2bf(v.y); o.z = f2bf(v.z); o.w = f2bf(v.w);
    ((ushort4*)dst)[t * 64 + l] = o;
  }
#pragma unroll
  for (int m = 1; m <= 32; m <<= 1) sq += __shfl_xor(sq, m);
  if (l == 0) cn2[wave] = sq;
}

// ---- K2v7: per-chunk sums GEMM, one 128-col slab per block; LDS-coalesced out ----
#define LDT2 132  // Vt row stride (bf16 elems)
#define LDM  136  // Mt row stride
__global__ __launch_bounds__(256) void k2_v7(
    const unsigned short* __restrict__ Vb, const int* __restrict__ labels,
    unsigned short* __restrict__ sums, int* __restrict__ cnts_t)
{
  __shared__ unsigned short Vt[128 * LDT2];   // 33792 B
  __shared__ unsigned short Mt[64 * LDM];     // 17408 B
  const int bi = blockIdx.x;
  const int m = bi / 6, g = bi % 6;
  const int tid = threadIdx.x;
  const int w = tid >> 6, l = tid & 63;
  const int r31 = l & 31, kh = l >> 5;

  // issue V-slab loads first; latency hides under Mt build
  uint4 vreg[8];
#pragma unroll
  for (int it = 0; it < 8; ++it) {
    int flat = it * 256 + tid;
    int row = flat >> 4, c = flat & 15;
    vreg[it] = *(const uint4*)(Vb + (size_t)(m * 128 + row) * D + g * 128 + c * 8);
  }

  for (int e = tid; e < 64 * LDM / 2; e += 256) ((unsigned int*)Mt)[e] = 0u;
  __syncthreads();
  if (tid < 128) Mt[labels[m * 128 + tid] * LDM + tid] = 0x3F80;
  __syncthreads();
  if (g == 0 && tid < 64) {
    int c = 0;
    for (int j = 0; j < 128; ++j) c += (Mt[tid * LDM + j] != 0);
    cnts_t[tid * NCF + m] = c;
  }

#pragma unroll
  for (int it = 0; it < 8; ++it) {
    int flat = it * 256 + tid;
    int row = flat >> 4, c = flat & 15;
    *(uint4*)(Vt + row * LDT2 + c * 8) = vreg[it];
  }
  __syncthreads();

  f32x16 acc0 = (f32x16){}, acc1 = (f32x16){};
#pragma unroll
  for (int kk = 0; kk < 8; ++kk) {
    bf16x8 a0 = *(const bf16x8*)(Mt + (r31) * LDM + kk * 16 + kh * 8);
    bf16x8 a1 = *(const bf16x8*)(Mt + (32 + r31) * LDM + kk * 16 + kh * 8);
    bf16x8 b;
#pragma unroll
    for (int r = 0; r < 8; ++r)
      b[r] = *(const short*)(Vt + (kk * 16 + kh * 8 + r) * LDT2 + w * 32 + r31);
    acc0 = __builtin_amdgcn_mfma_f32_32x32x16_bf16(a0, b, acc0, 0, 0, 0);
    acc1 = __builtin_amdgcn_mfma_f32_32x32x16_bf16(a1, b, acc1, 0, 0, 0);
  }

  // coalesced output: acc -> LDS (reuse Vt) -> row-contiguous global stores
  __syncthreads();
  unsigned short* So = Vt;   // [64][128]
#pragma unroll
  for (int q = 0; q < 16; ++q) {
    int kc = (q & 3) + 8 * (q >> 2) + 4 * kh;
    So[kc * 128 + w * 32 + r31]        = f2bf(acc0[q]);
    So[(32 + kc) * 128 + w * 32 + r31] = f2bf(acc1[q]);
  }
  __syncthreads();
  unsigned short* sp = sums + (size_t)m * (K * D) + g * 128;
#pragma unroll
  for (int it = 0; it < 4; ++it) {
    int flat = it * 256 + tid;
    int row = flat >> 4, c = flat & 15;
    *(uint4*)(sp + (size_t)row * D + c * 8) = *(const uint4*)(So + row * 128 + c * 8);
  }
}

// ---- K3a: level-1 exclusive scan over 16 chunks, IN PLACE on bf16 sums ----
__global__ __launch_bounds__(256) void k3a_scan_lo(
    unsigned short* __restrict__ sums, float* __restrict__ aux)
{
  const int g  = blockIdx.x / 96;
  const int cp = (blockIdx.x % 96) * 256 + threadIdx.x;  // column pair
  const int col = cp * 2;
  float run0 = 0.f, run1 = 0.f;
  for (int m = g * 16; m < g * 16 + 16; ++m) {
    size_t idx = (size_t)m * (K * D) + col;
    unsigned u = *(const unsigned*)(sums + idx);
    float t0 = bflo(u), t1 = bfhi(u);
    *(unsigned*)(sums + idx) = (unsigned)f2bf(run0) | ((unsigned)f2bf(run1) << 16);
    run0 += t0; run1 += t1;
  }
  aux[(size_t)g * (K * D) + col]     = run0;
  aux[(size_t)g * (K * D) + col + 1] = run1;
}

// ---- K3b+: scan group totals (f32); block 192 scans cnts ----
__global__ __launch_bounds__(256) void k3b_plus(
    float* __restrict__ aux, int* __restrict__ cnts_t)
{
  if (blockIdx.x == 192) {
    if (threadIdx.x < K) {
      int k = threadIdx.x;
      int run = 0;
      int* p = cnts_t + k * NCF;
      for (int mm = 0; mm < NCF; ++mm) { int t = p[mm]; p[mm] = run; run += t; }
    }
    return;
  }
  int col = blockIdx.x * 256 + threadIdx.x;
  float run = 0.f;
  for (int g = 0; g < 16; ++g) {
    size_t idx = (size_t)g * (K * D) + col;
    float t = aux[idx]; aux[idx] = run; run += t;
  }
}

// ---- K4v7: fused GEMMs + epilogue; DOUBLE-BUFFERED LDS, 1 barrier/slab ----
#define LDV2 136  // bf16 row stride for 128-col tiles
#define LDD  132  // f32 dot LDS stride
#define BUFW (2 * 128 * LDV2)   // one buffer = Vt|Bt
__global__ __launch_bounds__(1024, 4) void k4_v7(
    const unsigned short* __restrict__ Vb, const unsigned short* __restrict__ base,
    const float* __restrict__ aux, const unsigned short* __restrict__ cavgb,
    const int* __restrict__ labels, const int* __restrict__ cnts_t,
    const float* __restrict__ cn2, float* __restrict__ out)
{
  __shared__ unsigned short smem[2 * BUFW];   // 139264 B
  __shared__ float pvL[128];
  __shared__ float bn2L[64];
  __shared__ int   labL[128];
  __shared__ float chk[16][64];
  const int m = blockIdx.x;
  const int g = m >> 4;
  const int tid = threadIdx.x;
  const int w = tid >> 6, l = tid & 63;
  const int r31 = l & 31, kh = l >> 5;
  const int wr = w & 3;    // output row-tile (32 rows)
  const int wc = w >> 2;   // output col-tile (32 cols)

  if (tid < 128) labL[tid] = labels[m * 128 + tid];
  if (tid < 64) bn2L[tid] = 0.f;
  __syncthreads();

  f32x16 accP = (f32x16){}, accS = (f32x16){};

  uint4 vreg[2], breg, creg;
  float4 areg[2];

#define PREF(sx) do {                                                          \
    _Pragma("unroll")                                                          \
    for (int it = 0; it < 2; ++it) {                                           \
      int flat = it * 1024 + tid;                                              \
      int row = flat >> 4, c = flat & 15;                                      \
      vreg[it] = *(const uint4*)(Vb + (size_t)(m * 128 + row) * D + (sx) * 128 + c * 8); \
      if (it == 0) {                                                           \
        breg = *(const uint4*)(base + ((size_t)m * K + row) * D + (sx) * 128 + c * 8); \
        const float* ap = aux + ((size_t)g * K + row) * D + (sx) * 128 + c * 8; \
        areg[0] = *(const float4*)ap;                                          \
        areg[1] = *(const float4*)(ap + 4);                                    \
      } else {                                                                 \
        creg = *(const uint4*)(cavgb + (size_t)(row - 64) * D + (sx) * 128 + c * 8); \
      }                                                                        \
    }                                                                          \
  } while (0)

#define WRITEB(pb) do {                                                        \
    unsigned short* Vt_ = smem + (pb) * BUFW;                                  \
    unsigned short* Bt_ = Vt_ + 128 * LDV2;                                    \
    _Pragma("unroll")                                                          \
    for (int it = 0; it < 2; ++it) {                                           \
      int flat = it * 1024 + tid;                                              \
      int row = flat >> 4, c = flat & 15;                                      \
      *(uint4*)(Vt_ + row * LDV2 + c * 8) = vreg[it];                          \
      if (it == 0) {                                                           \
        uint4 ub = breg;                                                       \
        float4 af0 = areg[0], af1 = areg[1];                                   \
        float f0 = bflo(ub.x) + af0.x, f1 = bfhi(ub.x) + af0.y;                \
        float f2 = bflo(ub.y) + af0.z, f3 = bfhi(ub.y) + af0.w;                \
        float f4 = bflo(ub.z) + af1.x, f5 = bfhi(ub.z) + af1.y;                \
        float f6 = bflo(ub.w) + af1.z, f7 = bfhi(ub.w) + af1.w;                \
        float sq = f0*f0 + f1*f1 + f2*f2 + f3*f3 + f4*f4 + f5*f5 + f6*f6 + f7*f7; \
        sq += __shfl_xor(sq, 1); sq += __shfl_xor(sq, 2);                      \
        sq += __shfl_xor(sq, 4); sq += __shfl_xor(sq, 8);                      \
        if ((l & 15) == 0) atomicAdd(&bn2L[row], sq);                          \
        uint4 u;                                                               \
        u.x = (unsigned)f2bf(f0) | ((unsigned)f2bf(f1) << 16);                 \
        u.y = (unsigned)f2bf(f2) | ((unsigned)f2bf(f3) << 16);                 \
        u.z = (unsigned)f2bf(f4) | ((unsigned)f2bf(f5) << 16);                 \
        u.w = (unsigned)f2bf(f6) | ((unsigned)f2bf(f7) << 16);                 \
        *(uint4*)(Bt_ + row * LDV2 + c * 8) = u;                               \
      } else {                                                                 \
        *(uint4*)(Bt_ + row * LDV2 + c * 8) = creg;                            \
      }                                                                        \
    }                                                                          \
  } while (0)

  PREF(0);
  WRITEB(0);
  PREF(1);
  __syncthreads();

  for (int s = 0; s < 6; ++s) {
    const int pb = s & 1;
    if (s < 5) WRITEB(pb ^ 1);     // write next slab (buffer free since barrier)
    if (s < 4) PREF(s + 2);        // refill regs; lands under MFMAs
    const unsigned short* Vt = smem + pb * BUFW;
    const unsigned short* Bt = Vt + 128 * LDV2;
#pragma unroll
    for (int kk = 0; kk < 8; ++kk) {
      bf16x8 av = *(const bf16x8*)(Vt + (32 * wr + r31) * LDV2 + kk * 16 + kh * 8);
      bf16x8 bB = *(const bf16x8*)(Bt + (32 * wc + r31) * LDV2 + kk * 16 + kh * 8);
      accP = __builtin_amdgcn_mfma_f32_32x32x16_bf16(av, bB, accP, 0, 0, 0);
      bf16x8 bV = *(const bf16x8*)(Vt + (32 * wc + r31) * LDV2 + kk * 16 + kh * 8);
      accS = __builtin_amdgcn_mfma_f32_32x32x16_bf16(av, bV, accS, 0, 0, 0);
    }
    __syncthreads();
  }
#undef PREF
#undef WRITEB

  // ---- pv from Gram diagonal (diag tiles: wr==wc) ----
  if (wr == wc && ((r31 >> 2) & 1) == kh) {
    int q = (r31 & 3) + 4 * (r31 >> 3);
    pvL[32 * wr + r31] = accS[q];
  }

  // ---- masked S -> bf16 into buf0.Vt; one-hot Mt into buf0.Bt ----
  {
    unsigned short* Vt = smem;
    unsigned short* Bt = smem + 128 * LDV2;
#pragma unroll
    for (int q = 0; q < 16; ++q) {
      int i = 32 * wr + (q & 3) + 8 * (q >> 2) + 4 * kh;
      int j = 32 * wc + r31;
      Vt[i * LDV2 + j] = (j < i) ? f2bf(accS[q]) : (unsigned short)0;
    }
    int j = tid & 127;
    int lab = labL[j];
    int kb = (tid >> 7) * 8;
#pragma unroll
    for (int kk = 0; kk < 8; ++kk) {
      int k = kb + kk;
      Bt[k * LDV2 + j] = (lab == k) ? (unsigned short)0x3F80 : (unsigned short)0;
    }
  }
  __syncthreads();

  // ---- corr = tril_strict(S) @ onehot; waves 0-7 own the class-col tiles ----
  if (w < 8) {
    const unsigned short* Vt = smem;
    const unsigned short* Bt = smem + 128 * LDV2;
#pragma unroll
    for (int kk = 0; kk < 8; ++kk) {
      bf16x8 aS = *(const bf16x8*)(Vt + (32 * wr + r31) * LDV2 + kk * 16 + kh * 8);
      bf16x8 bM = *(const bf16x8*)(Bt + (32 * wc + r31) * LDV2 + kk * 16 + kh * 8);
      accP = __builtin_amdgcn_mfma_f32_32x32x16_bf16(aS, bM, accP, 0, 0, 0);
    }
  }
  __syncthreads();

  // ---- dot matrix -> LDS ----
  float* dotL = (float*)smem;
#pragma unroll
  for (int q = 0; q < 16; ++q) {
    int i = 32 * wr + (q & 3) + 8 * (q >> 2) + 4 * kh;
    dotL[i * LDD + 32 * wc + r31] = accP[q];
  }
  __syncthreads();

  // ---- wave 0: norm-recurrence checkpoints every 8 rows ----
  if (w == 0) {
    int k = l;
    bool seen = cnts_t[k * NCF + m] > 0;
    float n = seen ? bn2L[k] : 0.f;
    for (int seg = 0; seg < 16; ++seg) {
      chk[seg][k] = seen ? n : -1.f;
      if (seg == 15) break;
      for (int j = seg * 8; j < seg * 8 + 8; ++j) {
        float dS = dotL[j * LDD + k];
        float pvj = pvL[j];
        if (labL[j] == k) {
          n = seen ? (n + 2.f * dS + pvj) : pvj;
          seen = true;
        }
      }
    }
  }
  __syncthreads();

  // ---- all 16 waves: emit 8-row segment from checkpoint ----
  {
    int k = l;
    float st = chk[w][k];
    bool seen = st >= 0.f;
    float n = seen ? st : 0.f;
    float cnk = cn2[k];
    int jb = w * 8;
    for (int j = jb; j < jb + 8; ++j) {
      float dS = dotL[j * LDD + k];
      float dC = dotL[j * LDD + 64 + k];
      float pvj = pvL[j];
      int lab = labL[j];
      float val = seen ? dS : dC;
      float nn  = seen ? n : cnk;
      out[(size_t)(m * 128 + j) * K + k] = val * rsqrtf(fmaxf(nn * pvj, 1e-30f));
      if (lab == k) {
        n = seen ? (n + 2.f * dS + pvj) : pvj;
        seen = true;
      }
    }
  }
}

// =====================================================================
// FALLBACK PATH — round-1 pipeline, verbatim (known-correct)
// =====================================================================
__global__ __launch_bounds__(256) void ph1_chunk_sums(
    const float* __restrict__ inputs, const int* __restrict__ labels,
    float* __restrict__ sums, int* __restrict__ cnts, int NC, int C)
{
  __shared__ float acc[4 * K * 64];
  __shared__ int   hist[4 * K];
  const int bi    = blockIdx.x;
  const int chunk = bi / 12, slice = bi % 12;
  const int w = threadIdx.x >> 6, l = threadIdx.x & 63;

  for (int e = threadIdx.x; e < 4 * K * 64; e += 256) acc[e] = 0.f;
  hist[threadIdx.x] = 0;
  __syncthreads();

  const int C4 = C >> 2;
  const long long rbase = (long long)chunk * C + (long long)w * C4;
  float* accw = acc + w * (K * 64);
  for (int j = 0; j < C4; ++j) {
    long long r = rbase + j;
    int lab = labels[r];
    float v = inputs[r * D + slice * 64 + l];
    accw[lab * 64 + l] += v;
    if (slice == 0 && l == 0) hist[w * K + lab]++;
  }
  __syncthreads();

  float* sp = sums + (long long)chunk * (K * D) + slice * 64;
  for (int e = threadIdx.x; e < K * 64; e += 256) {
    int k = e >> 6, dl = e & 63;
    float s = acc[0*K*64 + e] + acc[1*K*64 + e] + acc[2*K*64 + e] + acc[3*K*64 + e];
    sp[k * D + dl] = s;
  }
  if (slice == 0 && threadIdx.x < K) {
    cnts[chunk * K + threadIdx.x] =
        hist[0*K + threadIdx.x] + hist[1*K + threadIdx.x] +
        hist[2*K + threadIdx.x] + hist[3*K + threadIdx.x];
  }
}

__global__ __launch_bounds__(256) void ph2a_scan_sums(float* __restrict__ sums, int NC)
{
  const int tid = blockIdx.x * 256 + threadIdx.x;
  float run = 0.f;
  for (int m = 0; m < NC; ++m) {
    long long idx = (long long)m * (K * D) + tid;
    float t = sums[idx];
    sums[idx] = run;
    run += t;
  }
}

__global__ void ph2b_scan_cnts(int* __restrict__ cnts, int NC)
{
  const int k = threadIdx.x;
  int run = 0;
  for (int m = 0; m < NC; ++m) {
    int t = cnts[m * K + k];
    cnts[m * K + k] = run;
    run += t;
  }
}

__global__ __launch_bounds__(256, 4) void ph3_scan(
    const float* __restrict__ inputs, const int* __restrict__ labels,
    const float* __restrict__ cavg, const float* __restrict__ base,
    const int* __restrict__ cnts, float* __restrict__ out, int NC, int C)
{
  const int bi = blockIdx.x;
  int chunk, quad;
  if (NC >= 8) {
    int xcd = bi & 7, slot = bi >> 3;
    chunk = xcd * (NC >> 3) + (slot >> 2);
    quad  = slot & 3;
  } else {
    chunk = bi >> 2; quad = bi & 3;
  }
  const int w = threadIdx.x >> 6, l = threadIdx.x & 63;
  const int k0 = (quad * 4 + w) * 4;

  const int cb = chunk * K + k0;
  bool vg0 = (cnts[cb+0] == 0), vg1 = (cnts[cb+1] == 0);
  bool vg2 = (cnts[cb+2] == 0), vg3 = (cnts[cb+3] == 0);

  const float4* bp = (const float4*)base + (long long)chunk * (K * D4);
  const float4* cp = (const float4*)cavg;

  float4 A0[3], A1[3], A2[3], A3[3];
#pragma unroll
  for (int t = 0; t < 3; ++t) {
    int o = t * 64 + l;
    A0[t] = vg0 ? cp[(k0+0)*D4 + o] : bp[(k0+0)*D4 + o];
    A1[t] = vg1 ? cp[(k0+1)*D4 + o] : bp[(k0+1)*D4 + o];
    A2[t] = vg2 ? cp[(k0+2)*D4 + o] : bp[(k0+2)*D4 + o];
    A3[t] = vg3 ? cp[(k0+3)*D4 + o] : bp[(k0+3)*D4 + o];
  }
  float n0 = 0.f, n1 = 0.f, n2 = 0.f, n3 = 0.f;
#pragma unroll
  for (int t = 0; t < 3; ++t) {
    n0 += d4f(A0[t], A0[t]); n1 += d4f(A1[t], A1[t]);
    n2 += d4f(A2[t], A2[t]); n3 += d4f(A3[t], A3[t]);
  }
#pragma unroll
  for (int m = 1; m <= 32; m <<= 1) {
    n0 += __shfl_xor(n0, m); n1 += __shfl_xor(n1, m);
    n2 += __shfl_xor(n2, m); n3 += __shfl_xor(n3, m);
  }

  const long long ibase = (long long)chunk * C;
  for (int j = 0; j < C; ++j) {
    const long long i = ibase + j;
    const int lab = labels[i];
    const float4* vp = (const float4*)inputs + i * D4;
    float4 v0 = vp[l], v1 = vp[64 + l], v2 = vp[128 + l];

    float p0 = d4f(A0[0], v0) + d4f(A0[1], v1) + d4f(A0[2], v2);
    float p1 = d4f(A1[0], v0) + d4f(A1[1], v1) + d4f(A1[2], v2);
    float p2 = d4f(A2[0], v0) + d4f(A2[1], v1) + d4f(A2[2], v2);
    float p3 = d4f(A3[0], v0) + d4f(A3[1], v1) + d4f(A3[2], v2);
    float pv = d4f(v0, v0) + d4f(v1, v1) + d4f(v2, v2);
#pragma unroll
    for (int m = 1; m <= 32; m <<= 1) {
      p0 += __shfl_xor(p0, m); p1 += __shfl_xor(p1, m);
      p2 += __shfl_xor(p2, m); p3 += __shfl_xor(p3, m);
      pv += __shfl_xor(pv, m);
    }
    if (l < 4) {
      float ps = (l == 0) ? p0 : (l == 1) ? p1 : (l == 2) ? p2 : p3;
      float ns = (l == 0) ? n0 : (l == 1) ? n1 : (l == 2) ? n2 : n3;
      out[i * K + k0 + l] = ps * rsqrtf(fmaxf(ns * pv, 1e-30f));
    }
#define UPD(idx) do { \
      if (vg##idx) { A##idx[0]=v0; A##idx[1]=v1; A##idx[2]=v2; n##idx = pv; vg##idx = false; } \
      else { A##idx[0]=a4(A##idx[0],v0); A##idx[1]=a4(A##idx[1],v1); A##idx[2]=a4(A##idx[2],v2); \
             n##idx += 2.f * p##idx + pv; } } while (0)
    if      (lab == k0 + 0) UPD(0);
    else if (lab == k0 + 1) UPD(1);
    else if (lab == k0 + 2) UPD(2);
    else if (lab == k0 + 3) UPD(3);
#undef UPD
  }
}

// =====================================================================
extern "C" void kernel_launch(void* const* d_in, const int* in_sizes, int n_in,
                              void* d_out, int out_size, void* d_ws, size_t ws_size,
                              hipStream_t stream)
{
  const float* inputs = (const float*)d_in[0];
  const int*   labels = (const int*)d_in[1];
  const float* cavg   = (const float*)d_in[2];
  float* out = (float*)d_out;
  const int N = in_sizes[1];

  const size_t szVb    = (size_t)NF * D * 2;      // 50.3 MB
  const size_t szSums  = (size_t)NCF * K * D * 2; // 25.2 MB (bf16, scanned in place)
  const size_t szAux   = (size_t)16 * K * D * 4;  // 3.1 MB
  const size_t szCnt   = (size_t)K * NCF * 4;
  const size_t szCavgb = (size_t)K * D * 2;
  const size_t szCn2   = (size_t)K * 4;
  size_t need = szVb + szSums + szAux + szCnt + szCavgb + szCn2 + 8 * 256;

  if (N == NF && in_sizes[2] == K * D && ws_size >= need) {
    char* p = (char*)d_ws;
    auto take = [&](size_t b) { char* r = p; p += (b + 255) & ~(size_t)255; return r; };
    unsigned short* Vb    = (unsigned short*)take(szVb);
    unsigned short* sums  = (unsigned short*)take(szSums);
    float*          aux   = (float*)take(szAux);
    int*            cnts  = (int*)take(szCnt);
    unsigned short* cavgb = (unsigned short*)take(szCavgb);
    float*          cn2   = (float*)take(szCn2);

    hipLaunchKernelGGL(k1_all, dim3(NBV + 16), dim3(256), 0, stream,
                       inputs, cavg, Vb, cavgb, cn2);
    hipLaunchKernelGGL(k2_v7, dim3(NCF * 6), dim3(256), 0, stream,
                       Vb, labels, sums, cnts);
    hipLaunchKernelGGL(k3a_scan_lo, dim3(16 * 96), dim3(256), 0, stream, sums, aux);
    hipLaunchKernelGGL(k3b_plus, dim3(193), dim3(256), 0, stream, aux, cnts);
    hipLaunchKernelGGL(k4_v7, dim3(NCF), dim3(1024), 0, stream,
                       Vb, sums, aux, cavgb, labels, cnts, cn2, out);
    return;
  }

  // ---------------- fallback: round-1 pipeline ----------------
  int NC = 256;
  while (NC > 1) {
    size_t nd = (size_t)NC * K * D * 4 + (size_t)NC * K * 4;
    if (nd <= ws_size && (N % (NC * 4)) == 0) break;
    NC >>= 1;
  }
  const int C = N / NC;
  float* d_sums = (float*)d_ws;
  int*   d_cnts = (int*)((char*)d_ws + (size_t)NC * K * D * 4);

  hipLaunchKernelGGL(ph1_chunk_sums, dim3(NC * 12), dim3(256), 0, stream,
                     inputs, labels, d_sums, d_cnts, NC, C);
  hipLaunchKernelGGL(ph2a_scan_sums, dim3((K * D) / 256), dim3(256), 0, stream,
                     d_sums, NC);
  hipLaunchKernelGGL(ph2b_scan_cnts, dim3(1), dim3(64), 0, stream,
                     d_cnts, NC);
  hipLaunchKernelGGL(ph3_scan, dim3(NC * 4), dim3(256), 0, stream,
                     inputs, labels, cavg, d_sums, d_cnts, out, NC, C);
}

// Round 11
// 87.408 us; speedup vs baseline: 1.8363x; 1.2227x over previous
//
#include <hip/hip_runtime.h>
#include <cstddef>

#define K 64
#define D 768
#define D4 192   // D/4

__device__ __forceinline__ float d4f(float4 a, float4 b) {
  return a.x*b.x + a.y*b.y + a.z*b.z + a.w*b.w;
}
__device__ __forceinline__ float4 a4(float4 a, float4 b) {
  return make_float4(a.x+b.x, a.y+b.y, a.z+b.z, a.w+b.w);
}
__device__ __forceinline__ unsigned short f2bf(float x) {
  unsigned int u = __float_as_uint(x);
  unsigned int r = (u + 0x7FFFu + ((u >> 16) & 1u)) >> 16;
  return (unsigned short)r;
}
__device__ __forceinline__ float bflo(unsigned u) { return __uint_as_float(u << 16); }
__device__ __forceinline__ float bfhi(unsigned u) { return __uint_as_float(u & 0xFFFF0000u); }

typedef __attribute__((ext_vector_type(8)))  short bf16x8;
typedef __attribute__((ext_vector_type(16))) float f32x16;

// =====================================================================
// FAST PATH (N=32768, NC=256, C=128)
// =====================================================================
#define NCF 256
#define CF  128
#define NF  32768

// ---- K1c: cast cavg to bf16 + exact ||row||^2 (tiny) ----
__global__ __launch_bounds__(256) void k1c(
    const float* __restrict__ cavg, unsigned short* __restrict__ cavgb,
    float* __restrict__ cn2)
{
  int wave = blockIdx.x * 4 + (threadIdx.x >> 6);
  int l = threadIdx.x & 63;
  if (wave >= K) return;
  const float* src = cavg + (size_t)wave * D;
  unsigned short* dst = cavgb + (size_t)wave * D;
  float sq = 0.f;
#pragma unroll
  for (int t = 0; t < 3; ++t) {
    float4 v = ((const float4*)src)[t * 64 + l];
    sq += v.x*v.x + v.y*v.y + v.z*v.z + v.w*v.w;
    ushort4 o; o.x = f2bf(v.x); o.y = f2bf(v.y); o.z = f2bf(v.z); o.w = f2bf(v.w);
    ((ushort4*)dst)[t * 64 + l] = o;
  }
#pragma unroll
  for (int m = 1; m <= 32; m <<= 1) sq += __shfl_xor(sq, m);
  if (l == 0) cn2[wave] = sq;
}

// ---- K2v9: fused cast + per-chunk sums GEMM; one 128-col slab per block ----
// Reads f32 inputs (coalesced, prefetched across Mt build), emits Vb (bf16)
// + sums slab (bf16, LDS-coalesced 256B row stores). Structure = k2_v7.
#define LDT2 132  // Vt row stride (bf16 elems)
#define LDM  136  // Mt row stride
__global__ __launch_bounds__(256) void k2_v9(
    const float* __restrict__ inputs, const int* __restrict__ labels,
    unsigned short* __restrict__ Vb, unsigned short* __restrict__ sums,
    int* __restrict__ cnts_t)
{
  __shared__ unsigned short Vt[128 * LDT2];   // 33792 B
  __shared__ unsigned short Mt[64 * LDM];     // 17408 B
  const int bi = blockIdx.x;
  const int m = bi / 6, g = bi % 6;
  const int tid = threadIdx.x;
  const int w = tid >> 6, l = tid & 63;
  const int r31 = l & 31, kh = l >> 5;

  // issue f32 slab loads first; latency hides under Mt build
  float4 fa[8], fb[8];
#pragma unroll
  for (int it = 0; it < 8; ++it) {
    int flat = it * 256 + tid;
    int row = flat >> 4, c8 = flat & 15;
    const float* src = inputs + (size_t)(m * 128 + row) * D + g * 128 + c8 * 8;
    fa[it] = *(const float4*)src;
    fb[it] = *(const float4*)(src + 4);
  }

  for (int e = tid; e < 64 * LDM / 2; e += 256) ((unsigned int*)Mt)[e] = 0u;
  __syncthreads();
  if (tid < 128) Mt[labels[m * 128 + tid] * LDM + tid] = 0x3F80;
  __syncthreads();
  if (g == 0 && tid < 64) {
    int c = 0;
    for (int j = 0; j < 128; ++j) c += (Mt[tid * LDM + j] != 0);
    cnts_t[tid * NCF + m] = c;
  }

  // convert + write Vt (LDS) and Vb (global, coalesced 16B/thread)
#pragma unroll
  for (int it = 0; it < 8; ++it) {
    int flat = it * 256 + tid;
    int row = flat >> 4, c8 = flat & 15;
    uint4 u;
    u.x = (unsigned)f2bf(fa[it].x) | ((unsigned)f2bf(fa[it].y) << 16);
    u.y = (unsigned)f2bf(fa[it].z) | ((unsigned)f2bf(fa[it].w) << 16);
    u.z = (unsigned)f2bf(fb[it].x) | ((unsigned)f2bf(fb[it].y) << 16);
    u.w = (unsigned)f2bf(fb[it].z) | ((unsigned)f2bf(fb[it].w) << 16);
    *(uint4*)(Vt + row * LDT2 + c8 * 8) = u;
    *(uint4*)(Vb + (size_t)(m * 128 + row) * D + g * 128 + c8 * 8) = u;
  }
  __syncthreads();

  f32x16 acc0 = (f32x16){}, acc1 = (f32x16){};
#pragma unroll
  for (int kk = 0; kk < 8; ++kk) {
    bf16x8 a0 = *(const bf16x8*)(Mt + (r31) * LDM + kk * 16 + kh * 8);
    bf16x8 a1 = *(const bf16x8*)(Mt + (32 + r31) * LDM + kk * 16 + kh * 8);
    bf16x8 b;
#pragma unroll
    for (int r = 0; r < 8; ++r)
      b[r] = *(const short*)(Vt + (kk * 16 + kh * 8 + r) * LDT2 + w * 32 + r31);
    acc0 = __builtin_amdgcn_mfma_f32_32x32x16_bf16(a0, b, acc0, 0, 0, 0);
    acc1 = __builtin_amdgcn_mfma_f32_32x32x16_bf16(a1, b, acc1, 0, 0, 0);
  }

  // coalesced output: acc -> LDS (reuse Vt) -> row-contiguous global stores
  __syncthreads();
  unsigned short* So = Vt;   // [64][128]
#pragma unroll
  for (int q = 0; q < 16; ++q) {
    int kc = (q & 3) + 8 * (q >> 2) + 4 * kh;
    So[kc * 128 + w * 32 + r31]        = f2bf(acc0[q]);
    So[(32 + kc) * 128 + w * 32 + r31] = f2bf(acc1[q]);
  }
  __syncthreads();
  unsigned short* sp = sums + (size_t)m * (K * D) + g * 128;
#pragma unroll
  for (int it = 0; it < 4; ++it) {
    int flat = it * 256 + tid;
    int row = flat >> 4, c = flat & 15;
    *(uint4*)(sp + (size_t)row * D + c * 8) = *(const uint4*)(So + row * 128 + c * 8);
  }
}

// ---- K3a: level-1 exclusive scan over 16 chunks, IN PLACE on bf16 sums ----
__global__ __launch_bounds__(256) void k3a_scan_lo(
    unsigned short* __restrict__ sums, float* __restrict__ aux)
{
  const int g  = blockIdx.x / 96;
  const int cp = (blockIdx.x % 96) * 256 + threadIdx.x;  // column pair
  const int col = cp * 2;
  float run0 = 0.f, run1 = 0.f;
  for (int m = g * 16; m < g * 16 + 16; ++m) {
    size_t idx = (size_t)m * (K * D) + col;
    unsigned u = *(const unsigned*)(sums + idx);
    float t0 = bflo(u), t1 = bfhi(u);
    *(unsigned*)(sums + idx) = (unsigned)f2bf(run0) | ((unsigned)f2bf(run1) << 16);
    run0 += t0; run1 += t1;
  }
  aux[(size_t)g * (K * D) + col]     = run0;
  aux[(size_t)g * (K * D) + col + 1] = run1;
}

// ---- K3b+: scan group totals (f32); block 192 scans cnts ----
__global__ __launch_bounds__(256) void k3b_plus(
    float* __restrict__ aux, int* __restrict__ cnts_t)
{
  if (blockIdx.x == 192) {
    if (threadIdx.x < K) {
      int k = threadIdx.x;
      int run = 0;
      int* p = cnts_t + k * NCF;
      for (int mm = 0; mm < NCF; ++mm) { int t = p[mm]; p[mm] = run; run += t; }
    }
    return;
  }
  int col = blockIdx.x * 256 + threadIdx.x;
  float run = 0.f;
  for (int g = 0; g < 16; ++g) {
    size_t idx = (size_t)g * (K * D) + col;
    float t = aux[idx]; aux[idx] = run; run += t;
  }
}

// ---- K4v7: fused GEMMs + epilogue; DOUBLE-BUFFERED LDS, 1 barrier/slab ----
#define LDV2 136  // bf16 row stride for 128-col tiles
#define LDD  132  // f32 dot LDS stride
#define BUFW (2 * 128 * LDV2)   // one buffer = Vt|Bt
__global__ __launch_bounds__(1024, 4) void k4_v7(
    const unsigned short* __restrict__ Vb, const unsigned short* __restrict__ base,
    const float* __restrict__ aux, const unsigned short* __restrict__ cavgb,
    const int* __restrict__ labels, const int* __restrict__ cnts_t,
    const float* __restrict__ cn2, float* __restrict__ out)
{
  __shared__ unsigned short smem[2 * BUFW];   // 139264 B
  __shared__ float pvL[128];
  __shared__ float bn2L[64];
  __shared__ int   labL[128];
  __shared__ float chk[16][64];
  const int m = blockIdx.x;
  const int g = m >> 4;
  const int tid = threadIdx.x;
  const int w = tid >> 6, l = tid & 63;
  const int r31 = l & 31, kh = l >> 5;
  const int wr = w & 3;    // output row-tile (32 rows)
  const int wc = w >> 2;   // output col-tile (32 cols)

  if (tid < 128) labL[tid] = labels[m * 128 + tid];
  if (tid < 64) bn2L[tid] = 0.f;
  __syncthreads();

  f32x16 accP = (f32x16){}, accS = (f32x16){};

  uint4 vreg[2], breg, creg;
  float4 areg[2];

#define PREF(sx) do {                                                          \
    _Pragma("unroll")                                                          \
    for (int it = 0; it < 2; ++it) {                                           \
      int flat = it * 1024 + tid;                                              \
      int row = flat >> 4, c = flat & 15;                                      \
      vreg[it] = *(const uint4*)(Vb + (size_t)(m * 128 + row) * D + (sx) * 128 + c * 8); \
      if (it == 0) {                                                           \
        breg = *(const uint4*)(base + ((size_t)m * K + row) * D + (sx) * 128 + c * 8); \
        const float* ap = aux + ((size_t)g * K + row) * D + (sx) * 128 + c * 8; \
        areg[0] = *(const float4*)ap;                                          \
        areg[1] = *(const float4*)(ap + 4);                                    \
      } else {                                                                 \
        creg = *(const uint4*)(cavgb + (size_t)(row - 64) * D + (sx) * 128 + c * 8); \
      }                                                                        \
    }                                                                          \
  } while (0)

#define WRITEB(pb) do {                                                        \
    unsigned short* Vt_ = smem + (pb) * BUFW;                                  \
    unsigned short* Bt_ = Vt_ + 128 * LDV2;                                    \
    _Pragma("unroll")                                                          \
    for (int it = 0; it < 2; ++it) {                                           \
      int flat = it * 1024 + tid;                                              \
      int row = flat >> 4, c = flat & 15;                                      \
      *(uint4*)(Vt_ + row * LDV2 + c * 8) = vreg[it];                          \
      if (it == 0) {                                                           \
        uint4 ub = breg;                                                       \
        float4 af0 = areg[0], af1 = areg[1];                                   \
        float f0 = bflo(ub.x) + af0.x, f1 = bfhi(ub.x) + af0.y;                \
        float f2 = bflo(ub.y) + af0.z, f3 = bfhi(ub.y) + af0.w;                \
        float f4 = bflo(ub.z) + af1.x, f5 = bfhi(ub.z) + af1.y;                \
        float f6 = bflo(ub.w) + af1.z, f7 = bfhi(ub.w) + af1.w;                \
        float sq = f0*f0 + f1*f1 + f2*f2 + f3*f3 + f4*f4 + f5*f5 + f6*f6 + f7*f7; \
        sq += __shfl_xor(sq, 1); sq += __shfl_xor(sq, 2);                      \
        sq += __shfl_xor(sq, 4); sq += __shfl_xor(sq, 8);                      \
        if ((l & 15) == 0) atomicAdd(&bn2L[row], sq);                          \
        uint4 u;                                                               \
        u.x = (unsigned)f2bf(f0) | ((unsigned)f2bf(f1) << 16);                 \
        u.y = (unsigned)f2bf(f2) | ((unsigned)f2bf(f3) << 16);                 \
        u.z = (unsigned)f2bf(f4) | ((unsigned)f2bf(f5) << 16);                 \
        u.w = (unsigned)f2bf(f6) | ((unsigned)f2bf(f7) << 16);                 \
        *(uint4*)(Bt_ + row * LDV2 + c * 8) = u;                               \
      } else {                                                                 \
        *(uint4*)(Bt_ + row * LDV2 + c * 8) = creg;                            \
      }                                                                        \
    }                                                                          \
  } while (0)

  PREF(0);
  WRITEB(0);
  PREF(1);
  __syncthreads();

  for (int s = 0; s < 6; ++s) {
    const int pb = s & 1;
    if (s < 5) WRITEB(pb ^ 1);     // write next slab (buffer free since barrier)
    if (s < 4) PREF(s + 2);        // refill regs; lands under MFMAs
    const unsigned short* Vt = smem + pb * BUFW;
    const unsigned short* Bt = Vt + 128 * LDV2;
#pragma unroll
    for (int kk = 0; kk < 8; ++kk) {
      bf16x8 av = *(const bf16x8*)(Vt + (32 * wr + r31) * LDV2 + kk * 16 + kh * 8);
      bf16x8 bB = *(const bf16x8*)(Bt + (32 * wc + r31) * LDV2 + kk * 16 + kh * 8);
      accP = __builtin_amdgcn_mfma_f32_32x32x16_bf16(av, bB, accP, 0, 0, 0);
      bf16x8 bV = *(const bf16x8*)(Vt + (32 * wc + r31) * LDV2 + kk * 16 + kh * 8);
      accS = __builtin_amdgcn_mfma_f32_32x32x16_bf16(av, bV, accS, 0, 0, 0);
    }
    __syncthreads();
  }
#undef PREF
#undef WRITEB

  // ---- pv from Gram diagonal (diag tiles: wr==wc) ----
  if (wr == wc && ((r31 >> 2) & 1) == kh) {
    int q = (r31 & 3) + 4 * (r31 >> 3);
    pvL[32 * wr + r31] = accS[q];
  }

  // ---- masked S -> bf16 into buf0.Vt; one-hot Mt into buf0.Bt ----
  {
    unsigned short* Vt = smem;
    unsigned short* Bt = smem + 128 * LDV2;
#pragma unroll
    for (int q = 0; q < 16; ++q) {
      int i = 32 * wr + (q & 3) + 8 * (q >> 2) + 4 * kh;
      int j = 32 * wc + r31;
      Vt[i * LDV2 + j] = (j < i) ? f2bf(accS[q]) : (unsigned short)0;
    }
    int j = tid & 127;
    int lab = labL[j];
    int kb = (tid >> 7) * 8;
#pragma unroll
    for (int kk = 0; kk < 8; ++kk) {
      int k = kb + kk;
      Bt[k * LDV2 + j] = (lab == k) ? (unsigned short)0x3F80 : (unsigned short)0;
    }
  }
  __syncthreads();

  // ---- corr = tril_strict(S) @ onehot; waves 0-7 own the class-col tiles ----
  if (w < 8) {
    const unsigned short* Vt = smem;
    const unsigned short* Bt = smem + 128 * LDV2;
#pragma unroll
    for (int kk = 0; kk < 8; ++kk) {
      bf16x8 aS = *(const bf16x8*)(Vt + (32 * wr + r31) * LDV2 + kk * 16 + kh * 8);
      bf16x8 bM = *(const bf16x8*)(Bt + (32 * wc + r31) * LDV2 + kk * 16 + kh * 8);
      accP = __builtin_amdgcn_mfma_f32_32x32x16_bf16(aS, bM, accP, 0, 0, 0);
    }
  }
  __syncthreads();

  // ---- dot matrix -> LDS ----
  float* dotL = (float*)smem;
#pragma unroll
  for (int q = 0; q < 16; ++q) {
    int i = 32 * wr + (q & 3) + 8 * (q >> 2) + 4 * kh;
    dotL[i * LDD + 32 * wc + r31] = accP[q];
  }
  __syncthreads();

  // ---- wave 0: norm-recurrence checkpoints every 8 rows ----
  if (w == 0) {
    int k = l;
    bool seen = cnts_t[k * NCF + m] > 0;
    float n = seen ? bn2L[k] : 0.f;
    for (int seg = 0; seg < 16; ++seg) {
      chk[seg][k] = seen ? n : -1.f;
      if (seg == 15) break;
      for (int j = seg * 8; j < seg * 8 + 8; ++j) {
        float dS = dotL[j * LDD + k];
        float pvj = pvL[j];
        if (labL[j] == k) {
          n = seen ? (n + 2.f * dS + pvj) : pvj;
          seen = true;
        }
      }
    }
  }
  __syncthreads();

  // ---- all 16 waves: emit 8-row segment from checkpoint ----
  {
    int k = l;
    float st = chk[w][k];
    bool seen = st >= 0.f;
    float n = seen ? st : 0.f;
    float cnk = cn2[k];
    int jb = w * 8;
    for (int j = jb; j < jb + 8; ++j) {
      float dS = dotL[j * LDD + k];
      float dC = dotL[j * LDD + 64 + k];
      float pvj = pvL[j];
      int lab = labL[j];
      float val = seen ? dS : dC;
      float nn  = seen ? n : cnk;
      out[(size_t)(m * 128 + j) * K + k] = val * rsqrtf(fmaxf(nn * pvj, 1e-30f));
      if (lab == k) {
        n = seen ? (n + 2.f * dS + pvj) : pvj;
        seen = true;
      }
    }
  }
}

// =====================================================================
// FALLBACK PATH — round-1 pipeline, verbatim (known-correct)
// =====================================================================
__global__ __launch_bounds__(256) void ph1_chunk_sums(
    const float* __restrict__ inputs, const int* __restrict__ labels,
    float* __restrict__ sums, int* __restrict__ cnts, int NC, int C)
{
  __shared__ float acc[4 * K * 64];
  __shared__ int   hist[4 * K];
  const int bi    = blockIdx.x;
  const int chunk = bi / 12, slice = bi % 12;
  const int w = threadIdx.x >> 6, l = threadIdx.x & 63;

  for (int e = threadIdx.x; e < 4 * K * 64; e += 256) acc[e] = 0.f;
  hist[threadIdx.x] = 0;
  __syncthreads();

  const int C4 = C >> 2;
  const long long rbase = (long long)chunk * C + (long long)w * C4;
  float* accw = acc + w * (K * 64);
  for (int j = 0; j < C4; ++j) {
    long long r = rbase + j;
    int lab = labels[r];
    float v = inputs[r * D + slice * 64 + l];
    accw[lab * 64 + l] += v;
    if (slice == 0 && l == 0) hist[w * K + lab]++;
  }
  __syncthreads();

  float* sp = sums + (long long)chunk * (K * D) + slice * 64;
  for (int e = threadIdx.x; e < K * 64; e += 256) {
    int k = e >> 6, dl = e & 63;
    float s = acc[0*K*64 + e] + acc[1*K*64 + e] + acc[2*K*64 + e] + acc[3*K*64 + e];
    sp[k * D + dl] = s;
  }
  if (slice == 0 && threadIdx.x < K) {
    cnts[chunk * K + threadIdx.x] =
        hist[0*K + threadIdx.x] + hist[1*K + threadIdx.x] +
        hist[2*K + threadIdx.x] + hist[3*K + threadIdx.x];
  }
}

__global__ __launch_bounds__(256) void ph2a_scan_sums(float* __restrict__ sums, int NC)
{
  const int tid = blockIdx.x * 256 + threadIdx.x;
  float run = 0.f;
  for (int m = 0; m < NC; ++m) {
    long long idx = (long long)m * (K * D) + tid;
    float t = sums[idx];
    sums[idx] = run;
    run += t;
  }
}

__global__ void ph2b_scan_cnts(int* __restrict__ cnts, int NC)
{
  const int k = threadIdx.x;
  int run = 0;
  for (int m = 0; m < NC; ++m) {
    int t = cnts[m * K + k];
    cnts[m * K + k] = run;
    run += t;
  }
}

__global__ __launch_bounds__(256, 4) void ph3_scan(
    const float* __restrict__ inputs, const int* __restrict__ labels,
    const float* __restrict__ cavg, const float* __restrict__ base,
    const int* __restrict__ cnts, float* __restrict__ out, int NC, int C)
{
  const int bi = blockIdx.x;
  int chunk, quad;
  if (NC >= 8) {
    int xcd = bi & 7, slot = bi >> 3;
    chunk = xcd * (NC >> 3) + (slot >> 2);
    quad  = slot & 3;
  } else {
    chunk = bi >> 2; quad = bi & 3;
  }
  const int w = threadIdx.x >> 6, l = threadIdx.x & 63;
  const int k0 = (quad * 4 + w) * 4;

  const int cb = chunk * K + k0;
  bool vg0 = (cnts[cb+0] == 0), vg1 = (cnts[cb+1] == 0);
  bool vg2 = (cnts[cb+2] == 0), vg3 = (cnts[cb+3] == 0);

  const float4* bp = (const float4*)base + (long long)chunk * (K * D4);
  const float4* cp = (const float4*)cavg;

  float4 A0[3], A1[3], A2[3], A3[3];
#pragma unroll
  for (int t = 0; t < 3; ++t) {
    int o = t * 64 + l;
    A0[t] = vg0 ? cp[(k0+0)*D4 + o] : bp[(k0+0)*D4 + o];
    A1[t] = vg1 ? cp[(k0+1)*D4 + o] : bp[(k0+1)*D4 + o];
    A2[t] = vg2 ? cp[(k0+2)*D4 + o] : bp[(k0+2)*D4 + o];
    A3[t] = vg3 ? cp[(k0+3)*D4 + o] : bp[(k0+3)*D4 + o];
  }
  float n0 = 0.f, n1 = 0.f, n2 = 0.f, n3 = 0.f;
#pragma unroll
  for (int t = 0; t < 3; ++t) {
    n0 += d4f(A0[t], A0[t]); n1 += d4f(A1[t], A1[t]);
    n2 += d4f(A2[t], A2[t]); n3 += d4f(A3[t], A3[t]);
  }
#pragma unroll
  for (int m = 1; m <= 32; m <<= 1) {
    n0 += __shfl_xor(n0, m); n1 += __shfl_xor(n1, m);
    n2 += __shfl_xor(n2, m); n3 += __shfl_xor(n3, m);
  }

  const long long ibase = (long long)chunk * C;
  for (int j = 0; j < C; ++j) {
    const long long i = ibase + j;
    const int lab = labels[i];
    const float4* vp = (const float4*)inputs + i * D4;
    float4 v0 = vp[l], v1 = vp[64 + l], v2 = vp[128 + l];

    float p0 = d4f(A0[0], v0) + d4f(A0[1], v1) + d4f(A0[2], v2);
    float p1 = d4f(A1[0], v0) + d4f(A1[1], v1) + d4f(A1[2], v2);
    float p2 = d4f(A2[0], v0) + d4f(A2[1], v1) + d4f(A2[2], v2);
    float p3 = d4f(A3[0], v0) + d4f(A3[1], v1) + d4f(A3[2], v2);
    float pv = d4f(v0, v0) + d4f(v1, v1) + d4f(v2, v2);
#pragma unroll
    for (int m = 1; m <= 32; m <<= 1) {
      p0 += __shfl_xor(p0, m); p1 += __shfl_xor(p1, m);
      p2 += __shfl_xor(p2, m); p3 += __shfl_xor(p3, m);
      pv += __shfl_xor(pv, m);
    }
    if (l < 4) {
      float ps = (l == 0) ? p0 : (l == 1) ? p1 : (l == 2) ? p2 : p3;
      float ns = (l == 0) ? n0 : (l == 1) ? n1 : (l == 2) ? n2 : n3;
      out[i * K + k0 + l] = ps * rsqrtf(fmaxf(ns * pv, 1e-30f));
    }
#define UPD(idx) do { \
      if (vg##idx) { A##idx[0]=v0; A##idx[1]=v1; A##idx[2]=v2; n##idx = pv; vg##idx = false; } \
      else { A##idx[0]=a4(A##idx[0],v0); A##idx[1]=a4(A##idx[1],v1); A##idx[2]=a4(A##idx[2],v2); \
             n##idx += 2.f * p##idx + pv; } } while (0)
    if      (lab == k0 + 0) UPD(0);
    else if (lab == k0 + 1) UPD(1);
    else if (lab == k0 + 2) UPD(2);
    else if (lab == k0 + 3) UPD(3);
#undef UPD
  }
}

// =====================================================================
extern "C" void kernel_launch(void* const* d_in, const int* in_sizes, int n_in,
                              void* d_out, int out_size, void* d_ws, size_t ws_size,
                              hipStream_t stream)
{
  const float* inputs = (const float*)d_in[0];
  const int*   labels = (const int*)d_in[1];
  const float* cavg   = (const float*)d_in[2];
  float* out = (float*)d_out;
  const int N = in_sizes[1];

  const size_t szVb    = (size_t)NF * D * 2;      // 50.3 MB
  const size_t szSums  = (size_t)NCF * K * D * 2; // 25.2 MB (bf16, scanned in place)
  const size_t szAux   = (size_t)16 * K * D * 4;  // 3.1 MB
  const size_t szCnt   = (size_t)K * NCF * 4;
  const size_t szCavgb = (size_t)K * D * 2;
  const size_t szCn2   = (size_t)K * 4;
  size_t need = szVb + szSums + szAux + szCnt + szCavgb + szCn2 + 8 * 256;

  if (N == NF && in_sizes[2] == K * D && ws_size >= need) {
    char* p = (char*)d_ws;
    auto take = [&](size_t b) { char* r = p; p += (b + 255) & ~(size_t)255; return r; };
    unsigned short* Vb    = (unsigned short*)take(szVb);
    unsigned short* sums  = (unsigned short*)take(szSums);
    float*          aux   = (float*)take(szAux);
    int*            cnts  = (int*)take(szCnt);
    unsigned short* cavgb = (unsigned short*)take(szCavgb);
    float*          cn2   = (float*)take(szCn2);

    hipLaunchKernelGGL(k1c, dim3(16), dim3(256), 0, stream, cavg, cavgb, cn2);
    hipLaunchKernelGGL(k2_v9, dim3(NCF * 6), dim3(256), 0, stream,
                       inputs, labels, Vb, sums, cnts);
    hipLaunchKernelGGL(k3a_scan_lo, dim3(16 * 96), dim3(256), 0, stream, sums, aux);
    hipLaunchKernelGGL(k3b_plus, dim3(193), dim3(256), 0, stream, aux, cnts);
    hipLaunchKernelGGL(k4_v7, dim3(NCF), dim3(1024), 0, stream,
                       Vb, sums, aux, cavgb, labels, cnts, cn2, out);
    return;
  }

  // ---------------- fallback: round-1 pipeline ----------------
  int NC = 256;
  while (NC > 1) {
    size_t nd = (size_t)NC * K * D * 4 + (size_t)NC * K * 4;
    if (nd <= ws_size && (N % (NC * 4)) == 0) break;
    NC >>= 1;
  }
  const int C = N / NC;
  float* d_sums = (float*)d_ws;
  int*   d_cnts = (int*)((char*)d_ws + (size_t)NC * K * D * 4);

  hipLaunchKernelGGL(ph1_chunk_sums, dim3(NC * 12), dim3(256), 0, stream,
                     inputs, labels, d_sums, d_cnts, NC, C);
  hipLaunchKernelGGL(ph2a_scan_sums, dim3((K * D) / 256), dim3(256), 0, stream,
                     d_sums, NC);
  hipLaunchKernelGGL(ph2b_scan_cnts, dim3(1), dim3(64), 0, stream,
                     d_cnts, NC);
  hipLaunchKernelGGL(ph3_scan, dim3(NC * 4), dim3(256), 0, stream,
                     inputs, labels, cavg, d_sums, d_cnts, out, NC, C);
}

// Round 12
// 78.790 us; speedup vs baseline: 2.0371x; 1.1094x over previous
//
#include <hip/hip_runtime.h>
#include <cstddef>

#define K 64
#define D 768
#define D4 192   // D/4

__device__ __forceinline__ float d4f(float4 a, float4 b) {
  return a.x*b.x + a.y*b.y + a.z*b.z + a.w*b.w;
}
__device__ __forceinline__ float4 a4(float4 a, float4 b) {
  return make_float4(a.x+b.x, a.y+b.y, a.z+b.z, a.w+b.w);
}
__device__ __forceinline__ unsigned short f2bf(float x) {
  unsigned int u = __float_as_uint(x);
  unsigned int r = (u + 0x7FFFu + ((u >> 16) & 1u)) >> 16;
  return (unsigned short)r;
}
__device__ __forceinline__ float bflo(unsigned u) { return __uint_as_float(u << 16); }
__device__ __forceinline__ float bfhi(unsigned u) { return __uint_as_float(u & 0xFFFF0000u); }

typedef __attribute__((ext_vector_type(8)))  short bf16x8;
typedef __attribute__((ext_vector_type(16))) float f32x16;

// =====================================================================
// FAST PATH (N=32768, NC=256, C=128)
// =====================================================================
#define NCF 256
#define CF  128
#define NF  32768

// ---- K1c: cast cavg to bf16 + exact ||row||^2 (tiny) ----
__global__ __launch_bounds__(256) void k1c(
    const float* __restrict__ cavg, unsigned short* __restrict__ cavgb,
    float* __restrict__ cn2)
{
  int wave = blockIdx.x * 4 + (threadIdx.x >> 6);
  int l = threadIdx.x & 63;
  if (wave >= K) return;
  const float* src = cavg + (size_t)wave * D;
  unsigned short* dst = cavgb + (size_t)wave * D;
  float sq = 0.f;
#pragma unroll
  for (int t = 0; t < 3; ++t) {
    float4 v = ((const float4*)src)[t * 64 + l];
    sq += v.x*v.x + v.y*v.y + v.z*v.z + v.w*v.w;
    ushort4 o; o.x = f2bf(v.x); o.y = f2bf(v.y); o.z = f2bf(v.z); o.w = f2bf(v.w);
    ((ushort4*)dst)[t * 64 + l] = o;
  }
#pragma unroll
  for (int m = 1; m <= 32; m <<= 1) sq += __shfl_xor(sq, m);
  if (l == 0) cn2[wave] = sq;
}

// ---- K2v10: fused cast + per-chunk sums GEMM; NO Vb output ----
#define LDT2 132  // Vt row stride (bf16 elems)
#define LDM  136  // Mt row stride
__global__ __launch_bounds__(256) void k2_v10(
    const float* __restrict__ inputs, const int* __restrict__ labels,
    unsigned short* __restrict__ sums, int* __restrict__ cnts_t)
{
  __shared__ unsigned short Vt[128 * LDT2];   // 33792 B
  __shared__ unsigned short Mt[64 * LDM];     // 17408 B
  const int bi = blockIdx.x;
  const int m = bi / 6, g = bi % 6;
  const int tid = threadIdx.x;
  const int w = tid >> 6, l = tid & 63;
  const int r31 = l & 31, kh = l >> 5;

  // issue f32 slab loads first; latency hides under Mt build
  float4 fa[8], fb[8];
#pragma unroll
  for (int it = 0; it < 8; ++it) {
    int flat = it * 256 + tid;
    int row = flat >> 4, c8 = flat & 15;
    const float* src = inputs + (size_t)(m * 128 + row) * D + g * 128 + c8 * 8;
    fa[it] = *(const float4*)src;
    fb[it] = *(const float4*)(src + 4);
  }

  for (int e = tid; e < 64 * LDM / 2; e += 256) ((unsigned int*)Mt)[e] = 0u;
  __syncthreads();
  if (tid < 128) Mt[labels[m * 128 + tid] * LDM + tid] = 0x3F80;
  __syncthreads();
  if (g == 0 && tid < 64) {
    int c = 0;
    for (int j = 0; j < 128; ++j) c += (Mt[tid * LDM + j] != 0);
    cnts_t[tid * NCF + m] = c;
  }

  // convert + write Vt (LDS only)
#pragma unroll
  for (int it = 0; it < 8; ++it) {
    int flat = it * 256 + tid;
    int row = flat >> 4, c8 = flat & 15;
    uint4 u;
    u.x = (unsigned)f2bf(fa[it].x) | ((unsigned)f2bf(fa[it].y) << 16);
    u.y = (unsigned)f2bf(fa[it].z) | ((unsigned)f2bf(fa[it].w) << 16);
    u.z = (unsigned)f2bf(fb[it].x) | ((unsigned)f2bf(fb[it].y) << 16);
    u.w = (unsigned)f2bf(fb[it].z) | ((unsigned)f2bf(fb[it].w) << 16);
    *(uint4*)(Vt + row * LDT2 + c8 * 8) = u;
  }
  __syncthreads();

  f32x16 acc0 = (f32x16){}, acc1 = (f32x16){};
#pragma unroll
  for (int kk = 0; kk < 8; ++kk) {
    bf16x8 a0 = *(const bf16x8*)(Mt + (r31) * LDM + kk * 16 + kh * 8);
    bf16x8 a1 = *(const bf16x8*)(Mt + (32 + r31) * LDM + kk * 16 + kh * 8);
    bf16x8 b;
#pragma unroll
    for (int r = 0; r < 8; ++r)
      b[r] = *(const short*)(Vt + (kk * 16 + kh * 8 + r) * LDT2 + w * 32 + r31);
    acc0 = __builtin_amdgcn_mfma_f32_32x32x16_bf16(a0, b, acc0, 0, 0, 0);
    acc1 = __builtin_amdgcn_mfma_f32_32x32x16_bf16(a1, b, acc1, 0, 0, 0);
  }

  // coalesced output: acc -> LDS (reuse Vt) -> row-contiguous global stores
  __syncthreads();
  unsigned short* So = Vt;   // [64][128]
#pragma unroll
  for (int q = 0; q < 16; ++q) {
    int kc = (q & 3) + 8 * (q >> 2) + 4 * kh;
    So[kc * 128 + w * 32 + r31]        = f2bf(acc0[q]);
    So[(32 + kc) * 128 + w * 32 + r31] = f2bf(acc1[q]);
  }
  __syncthreads();
  unsigned short* sp = sums + (size_t)m * (K * D) + g * 128;
#pragma unroll
  for (int it = 0; it < 4; ++it) {
    int flat = it * 256 + tid;
    int row = flat >> 4, c = flat & 15;
    *(uint4*)(sp + (size_t)row * D + c * 8) = *(const uint4*)(So + row * 128 + c * 8);
  }
}

// ---- K3a: level-1 exclusive scan over 16 chunks, IN PLACE on bf16 sums ----
__global__ __launch_bounds__(256) void k3a_scan_lo(
    unsigned short* __restrict__ sums, float* __restrict__ aux)
{
  const int g  = blockIdx.x / 96;
  const int cp = (blockIdx.x % 96) * 256 + threadIdx.x;  // column pair
  const int col = cp * 2;
  float run0 = 0.f, run1 = 0.f;
  for (int m = g * 16; m < g * 16 + 16; ++m) {
    size_t idx = (size_t)m * (K * D) + col;
    unsigned u = *(const unsigned*)(sums + idx);
    float t0 = bflo(u), t1 = bfhi(u);
    *(unsigned*)(sums + idx) = (unsigned)f2bf(run0) | ((unsigned)f2bf(run1) << 16);
    run0 += t0; run1 += t1;
  }
  aux[(size_t)g * (K * D) + col]     = run0;
  aux[(size_t)g * (K * D) + col + 1] = run1;
}

// ---- K3b+: scan group totals (f32); block 192 scans cnts ----
__global__ __launch_bounds__(256) void k3b_plus(
    float* __restrict__ aux, int* __restrict__ cnts_t)
{
  if (blockIdx.x == 192) {
    if (threadIdx.x < K) {
      int k = threadIdx.x;
      int run = 0;
      int* p = cnts_t + k * NCF;
      for (int mm = 0; mm < NCF; ++mm) { int t = p[mm]; p[mm] = run; run += t; }
    }
    return;
  }
  int col = blockIdx.x * 256 + threadIdx.x;
  float run = 0.f;
  for (int g = 0; g < 16; ++g) {
    size_t idx = (size_t)g * (K * D) + col;
    float t = aux[idx]; aux[idx] = run; run += t;
  }
}

// ---- K4v8: fused GEMMs + epilogue; V from f32 inputs; parallel seg-scan ----
#define LDV2 136  // bf16 row stride for 128-col tiles
#define LDD  132  // f32 dot LDS stride
#define BUFW (2 * 128 * LDV2)   // one buffer = Vt|Bt
__global__ __launch_bounds__(1024, 4) void k4_v8(
    const float* __restrict__ inputs, const unsigned short* __restrict__ base,
    const float* __restrict__ aux, const unsigned short* __restrict__ cavgb,
    const int* __restrict__ labels, const int* __restrict__ cnts_t,
    const float* __restrict__ cn2, float* __restrict__ out)
{
  __shared__ unsigned short smem[2 * BUFW];   // 139264 B
  __shared__ float pvL[128];
  __shared__ float bn2L[64];
  __shared__ int   labL[128];
  __shared__ float segA[16][64];
  __shared__ float segF[16][64];
  __shared__ float segP[16][64];
  __shared__ int   segH[16][64];
  const int m = blockIdx.x;
  const int g = m >> 4;
  const int tid = threadIdx.x;
  const int w = tid >> 6, l = tid & 63;
  const int r31 = l & 31, kh = l >> 5;
  const int wr = w & 3;    // output row-tile (32 rows)
  const int wc = w >> 2;   // output col-tile (32 cols)

  if (tid < 128) labL[tid] = labels[m * 128 + tid];
  if (tid < 64) bn2L[tid] = 0.f;
  __syncthreads();

  f32x16 accP = (f32x16){}, accS = (f32x16){};

  float4 vregf[4];       // V slab as f32: 4x (row, 4-col granule)
  uint4 breg, creg;
  float4 areg[2];

#define PREF(sx) do {                                                          \
    _Pragma("unroll")                                                          \
    for (int it = 0; it < 4; ++it) {                                           \
      int flat = it * 1024 + tid;                                              \
      int row = flat >> 5, c4 = flat & 31;                                     \
      vregf[it] = *(const float4*)(inputs + (size_t)(m * 128 + row) * D + (sx) * 128 + c4 * 4); \
    }                                                                          \
    _Pragma("unroll")                                                          \
    for (int it = 0; it < 2; ++it) {                                           \
      int flat = it * 1024 + tid;                                              \
      int row = flat >> 4, c = flat & 15;                                      \
      if (it == 0) {                                                           \
        breg = *(const uint4*)(base + ((size_t)m * K + row) * D + (sx) * 128 + c * 8); \
        const float* ap = aux + ((size_t)g * K + row) * D + (sx) * 128 + c * 8; \
        areg[0] = *(const float4*)ap;                                          \
        areg[1] = *(const float4*)(ap + 4);                                    \
      } else {                                                                 \
        creg = *(const uint4*)(cavgb + (size_t)(row - 64) * D + (sx) * 128 + c * 8); \
      }                                                                        \
    }                                                                          \
  } while (0)

#define WRITEB(pb) do {                                                        \
    unsigned short* Vt_ = smem + (pb) * BUFW;                                  \
    unsigned short* Bt_ = Vt_ + 128 * LDV2;                                    \
    _Pragma("unroll")                                                          \
    for (int it = 0; it < 4; ++it) {                                           \
      int flat = it * 1024 + tid;                                              \
      int row = flat >> 5, c4 = flat & 31;                                     \
      ushort4 o;                                                               \
      o.x = f2bf(vregf[it].x); o.y = f2bf(vregf[it].y);                        \
      o.z = f2bf(vregf[it].z); o.w = f2bf(vregf[it].w);                        \
      *(ushort4*)(Vt_ + row * LDV2 + c4 * 4) = o;                              \
    }                                                                          \
    _Pragma("unroll")                                                          \
    for (int it = 0; it < 2; ++it) {                                           \
      int flat = it * 1024 + tid;                                              \
      int row = flat >> 4, c = flat & 15;                                      \
      if (it == 0) {                                                           \
        uint4 ub = breg;                                                       \
        float4 af0 = areg[0], af1 = areg[1];                                   \
        float f0 = bflo(ub.x) + af0.x, f1 = bfhi(ub.x) + af0.y;                \
        float f2 = bflo(ub.y) + af0.z, f3 = bfhi(ub.y) + af0.w;                \
        float f4 = bflo(ub.z) + af1.x, f5 = bfhi(ub.z) + af1.y;                \
        float f6 = bflo(ub.w) + af1.z, f7 = bfhi(ub.w) + af1.w;                \
        float sq = f0*f0 + f1*f1 + f2*f2 + f3*f3 + f4*f4 + f5*f5 + f6*f6 + f7*f7; \
        sq += __shfl_xor(sq, 1); sq += __shfl_xor(sq, 2);                      \
        sq += __shfl_xor(sq, 4); sq += __shfl_xor(sq, 8);                      \
        if ((l & 15) == 0) atomicAdd(&bn2L[row], sq);                          \
        uint4 u;                                                               \
        u.x = (unsigned)f2bf(f0) | ((unsigned)f2bf(f1) << 16);                 \
        u.y = (unsigned)f2bf(f2) | ((unsigned)f2bf(f3) << 16);                 \
        u.z = (unsigned)f2bf(f4) | ((unsigned)f2bf(f5) << 16);                 \
        u.w = (unsigned)f2bf(f6) | ((unsigned)f2bf(f7) << 16);                 \
        *(uint4*)(Bt_ + row * LDV2 + c * 8) = u;                               \
      } else {                                                                 \
        *(uint4*)(Bt_ + row * LDV2 + c * 8) = creg;                            \
      }                                                                        \
    }                                                                          \
  } while (0)

  PREF(0);
  WRITEB(0);
  PREF(1);
  __syncthreads();

  for (int s = 0; s < 6; ++s) {
    const int pb = s & 1;
    if (s < 5) WRITEB(pb ^ 1);     // write next slab (buffer free since barrier)
    if (s < 4) PREF(s + 2);        // refill regs; lands under MFMAs
    const unsigned short* Vt = smem + pb * BUFW;
    const unsigned short* Bt = Vt + 128 * LDV2;
#pragma unroll
    for (int kk = 0; kk < 8; ++kk) {
      bf16x8 av = *(const bf16x8*)(Vt + (32 * wr + r31) * LDV2 + kk * 16 + kh * 8);
      bf16x8 bB = *(const bf16x8*)(Bt + (32 * wc + r31) * LDV2 + kk * 16 + kh * 8);
      accP = __builtin_amdgcn_mfma_f32_32x32x16_bf16(av, bB, accP, 0, 0, 0);
      if (wc <= wr) {   // strict-lower + diag tiles only (upper fully masked)
        bf16x8 bV = *(const bf16x8*)(Vt + (32 * wc + r31) * LDV2 + kk * 16 + kh * 8);
        accS = __builtin_amdgcn_mfma_f32_32x32x16_bf16(av, bV, accS, 0, 0, 0);
      }
    }
    __syncthreads();
  }
#undef PREF
#undef WRITEB

  // ---- pv from Gram diagonal (diag tiles: wr==wc) ----
  if (wr == wc && ((r31 >> 2) & 1) == kh) {
    int q = (r31 & 3) + 4 * (r31 >> 3);
    pvL[32 * wr + r31] = accS[q];
  }

  // ---- masked S -> bf16 into buf0.Vt; one-hot Mt into buf0.Bt ----
  {
    unsigned short* Vt = smem;
    unsigned short* Bt = smem + 128 * LDV2;
#pragma unroll
    for (int q = 0; q < 16; ++q) {
      int i = 32 * wr + (q & 3) + 8 * (q >> 2) + 4 * kh;
      int j = 32 * wc + r31;
      Vt[i * LDV2 + j] = (j < i) ? f2bf(accS[q]) : (unsigned short)0;
    }
    int j = tid & 127;
    int lab = labL[j];
    int kb = (tid >> 7) * 8;
#pragma unroll
    for (int kk = 0; kk < 8; ++kk) {
      int k = kb + kk;
      Bt[k * LDV2 + j] = (lab == k) ? (unsigned short)0x3F80 : (unsigned short)0;
    }
  }
  __syncthreads();

  // ---- corr = tril_strict(S) @ onehot; waves 0-7 own the class-col tiles ----
  if (w < 8) {
    const unsigned short* Vt = smem;
    const unsigned short* Bt = smem + 128 * LDV2;
#pragma unroll
    for (int kk = 0; kk < 8; ++kk) {
      bf16x8 aS = *(const bf16x8*)(Vt + (32 * wr + r31) * LDV2 + kk * 16 + kh * 8);
      bf16x8 bM = *(const bf16x8*)(Bt + (32 * wc + r31) * LDV2 + kk * 16 + kh * 8);
      accP = __builtin_amdgcn_mfma_f32_32x32x16_bf16(aS, bM, accP, 0, 0, 0);
    }
  }
  __syncthreads();

  // ---- dot matrix -> LDS ----
  float* dotL = (float*)smem;
#pragma unroll
  for (int q = 0; q < 16; ++q) {
    int i = 32 * wr + (q & 3) + 8 * (q >> 2) + 4 * kh;
    dotL[i * LDD + 32 * wc + r31] = accP[q];
  }
  __syncthreads();

  // ---- parallel segment summaries: wave w owns rows [8w, 8w+8), lane = class ----
  {
    int k = l;
    float A = 0.f, Fv = 0.f, Pv = 0.f;
    int has = 0;
    int jb = w * 8;
    for (int j = jb; j < jb + 8; ++j) {
      if (labL[j] == k) {
        float t = 2.f * dotL[j * LDD + k] + pvL[j];
        A += t;
        if (!has) { Fv = t; Pv = pvL[j]; has = 1; }
      }
    }
    segA[w][k] = A; segF[w][k] = Fv; segP[w][k] = Pv; segH[w][k] = has;
  }
  __syncthreads();

  // ---- fold prior segments, then emit 8-row segment ----
  {
    int k = l;
    bool seen = cnts_t[k * NCF + m] > 0;
    float n = seen ? bn2L[k] : 0.f;
    for (int ww = 0; ww < w; ++ww) {
      if (segH[ww][k]) {
        n = seen ? (n + segA[ww][k])
                 : (segP[ww][k] + segA[ww][k] - segF[ww][k]);
        seen = true;
      }
    }
    float cnk = cn2[k];
    int jb = w * 8;
    for (int j = jb; j < jb + 8; ++j) {
      float dS = dotL[j * LDD + k];
      float dC = dotL[j * LDD + 64 + k];
      float pvj = pvL[j];
      int lab = labL[j];
      float val = seen ? dS : dC;
      float nn  = seen ? n : cnk;
      out[(size_t)(m * 128 + j) * K + k] = val * rsqrtf(fmaxf(nn * pvj, 1e-30f));
      if (lab == k) {
        n = seen ? (n + 2.f * dS + pvj) : pvj;
        seen = true;
      }
    }
  }
}

// =====================================================================
// FALLBACK PATH — round-1 pipeline, verbatim (known-correct)
// =====================================================================
__global__ __launch_bounds__(256) void ph1_chunk_sums(
    const float* __restrict__ inputs, const int* __restrict__ labels,
    float* __restrict__ sums, int* __restrict__ cnts, int NC, int C)
{
  __shared__ float acc[4 * K * 64];
  __shared__ int   hist[4 * K];
  const int bi    = blockIdx.x;
  const int chunk = bi / 12, slice = bi % 12;
  const int w = threadIdx.x >> 6, l = threadIdx.x & 63;

  for (int e = threadIdx.x; e < 4 * K * 64; e += 256) acc[e] = 0.f;
  hist[threadIdx.x] = 0;
  __syncthreads();

  const int C4 = C >> 2;
  const long long rbase = (long long)chunk * C + (long long)w * C4;
  float* accw = acc + w * (K * 64);
  for (int j = 0; j < C4; ++j) {
    long long r = rbase + j;
    int lab = labels[r];
    float v = inputs[r * D + slice * 64 + l];
    accw[lab * 64 + l] += v;
    if (slice == 0 && l == 0) hist[w * K + lab]++;
  }
  __syncthreads();

  float* sp = sums + (long long)chunk * (K * D) + slice * 64;
  for (int e = threadIdx.x; e < K * 64; e += 256) {
    int k = e >> 6, dl = e & 63;
    float s = acc[0*K*64 + e] + acc[1*K*64 + e] + acc[2*K*64 + e] + acc[3*K*64 + e];
    sp[k * D + dl] = s;
  }
  if (slice == 0 && threadIdx.x < K) {
    cnts[chunk * K + threadIdx.x] =
        hist[0*K + threadIdx.x] + hist[1*K + threadIdx.x] +
        hist[2*K + threadIdx.x] + hist[3*K + threadIdx.x];
  }
}

__global__ __launch_bounds__(256) void ph2a_scan_sums(float* __restrict__ sums, int NC)
{
  const int tid = blockIdx.x * 256 + threadIdx.x;
  float run = 0.f;
  for (int m = 0; m < NC; ++m) {
    long long idx = (long long)m * (K * D) + tid;
    float t = sums[idx];
    sums[idx] = run;
    run += t;
  }
}

__global__ void ph2b_scan_cnts(int* __restrict__ cnts, int NC)
{
  const int k = threadIdx.x;
  int run = 0;
  for (int m = 0; m < NC; ++m) {
    int t = cnts[m * K + k];
    cnts[m * K + k] = run;
    run += t;
  }
}

__global__ __launch_bounds__(256, 4) void ph3_scan(
    const float* __restrict__ inputs, const int* __restrict__ labels,
    const float* __restrict__ cavg, const float* __restrict__ base,
    const int* __restrict__ cnts, float* __restrict__ out, int NC, int C)
{
  const int bi = blockIdx.x;
  int chunk, quad;
  if (NC >= 8) {
    int xcd = bi & 7, slot = bi >> 3;
    chunk = xcd * (NC >> 3) + (slot >> 2);
    quad  = slot & 3;
  } else {
    chunk = bi >> 2; quad = bi & 3;
  }
  const int w = threadIdx.x >> 6, l = threadIdx.x & 63;
  const int k0 = (quad * 4 + w) * 4;

  const int cb = chunk * K + k0;
  bool vg0 = (cnts[cb+0] == 0), vg1 = (cnts[cb+1] == 0);
  bool vg2 = (cnts[cb+2] == 0), vg3 = (cnts[cb+3] == 0);

  const float4* bp = (const float4*)base + (long long)chunk * (K * D4);
  const float4* cp = (const float4*)cavg;

  float4 A0[3], A1[3], A2[3], A3[3];
#pragma unroll
  for (int t = 0; t < 3; ++t) {
    int o = t * 64 + l;
    A0[t] = vg0 ? cp[(k0+0)*D4 + o] : bp[(k0+0)*D4 + o];
    A1[t] = vg1 ? cp[(k0+1)*D4 + o] : bp[(k0+1)*D4 + o];
    A2[t] = vg2 ? cp[(k0+2)*D4 + o] : bp[(k0+2)*D4 + o];
    A3[t] = vg3 ? cp[(k0+3)*D4 + o] : bp[(k0+3)*D4 + o];
  }
  float n0 = 0.f, n1 = 0.f, n2 = 0.f, n3 = 0.f;
#pragma unroll
  for (int t = 0; t < 3; ++t) {
    n0 += d4f(A0[t], A0[t]); n1 += d4f(A1[t], A1[t]);
    n2 += d4f(A2[t], A2[t]); n3 += d4f(A3[t], A3[t]);
  }
#pragma unroll
  for (int m = 1; m <= 32; m <<= 1) {
    n0 += __shfl_xor(n0, m); n1 += __shfl_xor(n1, m);
    n2 += __shfl_xor(n2, m); n3 += __shfl_xor(n3, m);
  }

  const long long ibase = (long long)chunk * C;
  for (int j = 0; j < C; ++j) {
    const long long i = ibase + j;
    const int lab = labels[i];
    const float4* vp = (const float4*)inputs + i * D4;
    float4 v0 = vp[l], v1 = vp[64 + l], v2 = vp[128 + l];

    float p0 = d4f(A0[0], v0) + d4f(A0[1], v1) + d4f(A0[2], v2);
    float p1 = d4f(A1[0], v0) + d4f(A1[1], v1) + d4f(A1[2], v2);
    float p2 = d4f(A2[0], v0) + d4f(A2[1], v1) + d4f(A2[2], v2);
    float p3 = d4f(A3[0], v0) + d4f(A3[1], v1) + d4f(A3[2], v2);
    float pv = d4f(v0, v0) + d4f(v1, v1) + d4f(v2, v2);
#pragma unroll
    for (int m = 1; m <= 32; m <<= 1) {
      p0 += __shfl_xor(p0, m); p1 += __shfl_xor(p1, m);
      p2 += __shfl_xor(p2, m); p3 += __shfl_xor(p3, m);
      pv += __shfl_xor(pv, m);
    }
    if (l < 4) {
      float ps = (l == 0) ? p0 : (l == 1) ? p1 : (l == 2) ? p2 : p3;
      float ns = (l == 0) ? n0 : (l == 1) ? n1 : (l == 2) ? n2 : n3;
      out[i * K + k0 + l] = ps * rsqrtf(fmaxf(ns * pv, 1e-30f));
    }
#define UPD(idx) do { \
      if (vg##idx) { A##idx[0]=v0; A##idx[1]=v1; A##idx[2]=v2; n##idx = pv; vg##idx = false; } \
      else { A##idx[0]=a4(A##idx[0],v0); A##idx[1]=a4(A##idx[1],v1); A##idx[2]=a4(A##idx[2],v2); \
             n##idx += 2.f * p##idx + pv; } } while (0)
    if      (lab == k0 + 0) UPD(0);
    else if (lab == k0 + 1) UPD(1);
    else if (lab == k0 + 2) UPD(2);
    else if (lab == k0 + 3) UPD(3);
#undef UPD
  }
}

// =====================================================================
extern "C" void kernel_launch(void* const* d_in, const int* in_sizes, int n_in,
                              void* d_out, int out_size, void* d_ws, size_t ws_size,
                              hipStream_t stream)
{
  const float* inputs = (const float*)d_in[0];
  const int*   labels = (const int*)d_in[1];
  const float* cavg   = (const float*)d_in[2];
  float* out = (float*)d_out;
  const int N = in_sizes[1];

  const size_t szSums  = (size_t)NCF * K * D * 2; // 25.2 MB (bf16, scanned in place)
  const size_t szAux   = (size_t)16 * K * D * 4;  // 3.1 MB
  const size_t szCnt   = (size_t)K * NCF * 4;
  const size_t szCavgb = (size_t)K * D * 2;
  const size_t szCn2   = (size_t)K * 4;
  size_t need = szSums + szAux + szCnt + szCavgb + szCn2 + 8 * 256;

  if (N == NF && in_sizes[2] == K * D && ws_size >= need) {
    char* p = (char*)d_ws;
    auto take = [&](size_t b) { char* r = p; p += (b + 255) & ~(size_t)255; return r; };
    unsigned short* sums  = (unsigned short*)take(szSums);
    float*          aux   = (float*)take(szAux);
    int*            cnts  = (int*)take(szCnt);
    unsigned short* cavgb = (unsigned short*)take(szCavgb);
    float*          cn2   = (float*)take(szCn2);

    hipLaunchKernelGGL(k1c, dim3(16), dim3(256), 0, stream, cavg, cavgb, cn2);
    hipLaunchKernelGGL(k2_v10, dim3(NCF * 6), dim3(256), 0, stream,
                       inputs, labels, sums, cnts);
    hipLaunchKernelGGL(k3a_scan_lo, dim3(16 * 96), dim3(256), 0, stream, sums, aux);
    hipLaunchKernelGGL(k3b_plus, dim3(193), dim3(256), 0, stream, aux, cnts);
    hipLaunchKernelGGL(k4_v8, dim3(NCF), dim3(1024), 0, stream,
                       inputs, sums, aux, cavgb, labels, cnts, cn2, out);
    return;
  }

  // ---------------- fallback: round-1 pipeline ----------------
  int NC = 256;
  while (NC > 1) {
    size_t nd = (size_t)NC * K * D * 4 + (size_t)NC * K * 4;
    if (nd <= ws_size && (N % (NC * 4)) == 0) break;
    NC >>= 1;
  }
  const int C = N / NC;
  float* d_sums = (float*)d_ws;
  int*   d_cnts = (int*)((char*)d_ws + (size_t)NC * K * D * 4);

  hipLaunchKernelGGL(ph1_chunk_sums, dim3(NC * 12), dim3(256), 0, stream,
                     inputs, labels, d_sums, d_cnts, NC, C);
  hipLaunchKernelGGL(ph2a_scan_sums, dim3((K * D) / 256), dim3(256), 0, stream,
                     d_sums, NC);
  hipLaunchKernelGGL(ph2b_scan_cnts, dim3(1), dim3(64), 0, stream,
                     d_cnts, NC);
  hipLaunchKernelGGL(ph3_scan, dim3(NC * 4), dim3(256), 0, stream,
                     inputs, labels, cavg, d_sums, d_cnts, out, NC, C);
}

// Round 13
// 72.531 us; speedup vs baseline: 2.2129x; 1.0863x over previous
//
#include <hip/hip_runtime.h>
#include <cstddef>

#define K 64
#define D 768
#define D4 192   // D/4

__device__ __forceinline__ float d4f(float4 a, float4 b) {
  return a.x*b.x + a.y*b.y + a.z*b.z + a.w*b.w;
}
__device__ __forceinline__ float4 a4(float4 a, float4 b) {
  return make_float4(a.x+b.x, a.y+b.y, a.z+b.z, a.w+b.w);
}
__device__ __forceinline__ unsigned short f2bf(float x) {
  unsigned int u = __float_as_uint(x);
  unsigned int r = (u + 0x7FFFu + ((u >> 16) & 1u)) >> 16;
  return (unsigned short)r;
}
__device__ __forceinline__ float bflo(unsigned u) { return __uint_as_float(u << 16); }
__device__ __forceinline__ float bfhi(unsigned u) { return __uint_as_float(u & 0xFFFF0000u); }

typedef __attribute__((ext_vector_type(8)))  short bf16x8;
typedef __attribute__((ext_vector_type(16))) float f32x16;

// =====================================================================
// FAST PATH (N=32768, NC=256, C=128)
// =====================================================================
#define NCF 256
#define CF  128
#define NF  32768

// ---- K2v11: fused cast + per-chunk sums GEMM; 64-col slabs, 4 blocks/CU ----
// grid = NCF*12 (+16 tail blocks doing the cavg cast). Bit-identical math to
// k2_v10: contraction spans all 128 chunk rows; slab width only splits d.
#define LDT3 68   // Vt row stride (bf16 elems) for 64-col slab
#define LDM  136  // Mt row stride
__global__ __launch_bounds__(256) void k2_v11(
    const float* __restrict__ inputs, const int* __restrict__ labels,
    const float* __restrict__ cavg, unsigned short* __restrict__ cavgb,
    float* __restrict__ cn2,
    unsigned short* __restrict__ sums, int* __restrict__ cnts_t)
{
  __shared__ unsigned short Vt[128 * LDT3];   // 17408 B (reused as So)
  __shared__ unsigned short Mt[64 * LDM];     // 17408 B
  __shared__ int hist[64];
  const int bi = blockIdx.x;
  const int tid = threadIdx.x;

  if (bi >= NCF * 12) {   // ---- cavg tail: cast + exact row norms ----
    int wave = (bi - NCF * 12) * 4 + (tid >> 6);
    int l = tid & 63;
    if (wave >= K) return;
    const float* src = cavg + (size_t)wave * D;
    unsigned short* dst = cavgb + (size_t)wave * D;
    float sq = 0.f;
#pragma unroll
    for (int t = 0; t < 3; ++t) {
      float4 v = ((const float4*)src)[t * 64 + l];
      sq += v.x*v.x + v.y*v.y + v.z*v.z + v.w*v.w;
      ushort4 o; o.x = f2bf(v.x); o.y = f2bf(v.y); o.z = f2bf(v.z); o.w = f2bf(v.w);
      ((ushort4*)dst)[t * 64 + l] = o;
    }
#pragma unroll
    for (int mm = 1; mm <= 32; mm <<= 1) sq += __shfl_xor(sq, mm);
    if (l == 0) cn2[wave] = sq;
    return;
  }

  const int m = bi / 12, g = bi % 12;
  const int w = tid >> 6, l = tid & 63;
  const int r31 = l & 31, kh = l >> 5;
  const int ch = w & 1;    // class-half (rows of output)
  const int cw = w >> 1;   // col-half (32-col tile within 64-col slab)

  // issue f32 slab loads first; latency hides under Mt build
  float4 fr[8];
#pragma unroll
  for (int it = 0; it < 8; ++it) {
    int flat = it * 256 + tid;
    int row = flat >> 4, c4 = flat & 15;
    fr[it] = *(const float4*)(inputs + (size_t)(m * 128 + row) * D + g * 64 + c4 * 4);
  }

  for (int e = tid; e < 64 * LDM / 2; e += 256) ((unsigned int*)Mt)[e] = 0u;
  if (tid < 64) hist[tid] = 0;
  __syncthreads();
  if (tid < 128) {
    int lab = labels[m * 128 + tid];
    Mt[lab * LDM + tid] = 0x3F80;   // 1.0 bf16
    if (g == 0) atomicAdd(&hist[lab], 1);
  }
  __syncthreads();
  if (g == 0 && tid < 64) cnts_t[tid * NCF + m] = hist[tid];

  // convert + write Vt (LDS only)
#pragma unroll
  for (int it = 0; it < 8; ++it) {
    int flat = it * 256 + tid;
    int row = flat >> 4, c4 = flat & 15;
    ushort4 o;
    o.x = f2bf(fr[it].x); o.y = f2bf(fr[it].y);
    o.z = f2bf(fr[it].z); o.w = f2bf(fr[it].w);
    *(ushort4*)(Vt + row * LDT3 + c4 * 4) = o;
  }
  __syncthreads();

  f32x16 acc = (f32x16){};
#pragma unroll
  for (int kk = 0; kk < 8; ++kk) {
    bf16x8 a = *(const bf16x8*)(Mt + (ch * 32 + r31) * LDM + kk * 16 + kh * 8);
    bf16x8 b;
#pragma unroll
    for (int r = 0; r < 8; ++r)
      b[r] = *(const short*)(Vt + (kk * 16 + kh * 8 + r) * LDT3 + cw * 32 + r31);
    acc = __builtin_amdgcn_mfma_f32_32x32x16_bf16(a, b, acc, 0, 0, 0);
  }

  // coalesced output: acc -> LDS (reuse Vt) -> row-contiguous global stores
  __syncthreads();
  unsigned short* So = Vt;   // [64][64]
#pragma unroll
  for (int q = 0; q < 16; ++q) {
    int kc = (q & 3) + 8 * (q >> 2) + 4 * kh;
    So[(ch * 32 + kc) * 64 + cw * 32 + r31] = f2bf(acc[q]);
  }
  __syncthreads();
  unsigned short* sp = sums + (size_t)m * (K * D) + g * 64;
#pragma unroll
  for (int it = 0; it < 2; ++it) {
    int flat = it * 256 + tid;
    int row = flat >> 3, c = flat & 7;
    *(uint4*)(sp + (size_t)row * D + c * 8) = *(const uint4*)(So + row * 64 + c * 8);
  }
}

// ---- K3a: level-1 exclusive scan over 16 chunks, IN PLACE on bf16 sums ----
__global__ __launch_bounds__(256) void k3a_scan_lo(
    unsigned short* __restrict__ sums, float* __restrict__ aux)
{
  const int g  = blockIdx.x / 96;
  const int cp = (blockIdx.x % 96) * 256 + threadIdx.x;  // column pair
  const int col = cp * 2;
  float run0 = 0.f, run1 = 0.f;
  for (int m = g * 16; m < g * 16 + 16; ++m) {
    size_t idx = (size_t)m * (K * D) + col;
    unsigned u = *(const unsigned*)(sums + idx);
    float t0 = bflo(u), t1 = bfhi(u);
    *(unsigned*)(sums + idx) = (unsigned)f2bf(run0) | ((unsigned)f2bf(run1) << 16);
    run0 += t0; run1 += t1;
  }
  aux[(size_t)g * (K * D) + col]     = run0;
  aux[(size_t)g * (K * D) + col + 1] = run1;
}

// ---- K3b+: scan group totals (f32); block 192 scans cnts ----
__global__ __launch_bounds__(256) void k3b_plus(
    float* __restrict__ aux, int* __restrict__ cnts_t)
{
  if (blockIdx.x == 192) {
    if (threadIdx.x < K) {
      int k = threadIdx.x;
      int run = 0;
      int* p = cnts_t + k * NCF;
      for (int mm = 0; mm < NCF; ++mm) { int t = p[mm]; p[mm] = run; run += t; }
    }
    return;
  }
  int col = blockIdx.x * 256 + threadIdx.x;
  float run = 0.f;
  for (int g = 0; g < 16; ++g) {
    size_t idx = (size_t)g * (K * D) + col;
    float t = aux[idx]; aux[idx] = run; run += t;
  }
}

// ---- K4v8: fused GEMMs + epilogue; V from f32 inputs; parallel seg-scan ----
#define LDV2 136  // bf16 row stride for 128-col tiles
#define LDD  132  // f32 dot LDS stride
#define BUFW (2 * 128 * LDV2)   // one buffer = Vt|Bt
__global__ __launch_bounds__(1024, 4) void k4_v8(
    const float* __restrict__ inputs, const unsigned short* __restrict__ base,
    const float* __restrict__ aux, const unsigned short* __restrict__ cavgb,
    const int* __restrict__ labels, const int* __restrict__ cnts_t,
    const float* __restrict__ cn2, float* __restrict__ out)
{
  __shared__ unsigned short smem[2 * BUFW];   // 139264 B
  __shared__ float pvL[128];
  __shared__ float bn2L[64];
  __shared__ int   labL[128];
  __shared__ float segA[16][64];
  __shared__ float segF[16][64];
  __shared__ float segP[16][64];
  __shared__ int   segH[16][64];
  const int m = blockIdx.x;
  const int g = m >> 4;
  const int tid = threadIdx.x;
  const int w = tid >> 6, l = tid & 63;
  const int r31 = l & 31, kh = l >> 5;
  const int wr = w & 3;    // output row-tile (32 rows)
  const int wc = w >> 2;   // output col-tile (32 cols)

  if (tid < 128) labL[tid] = labels[m * 128 + tid];
  if (tid < 64) bn2L[tid] = 0.f;
  __syncthreads();

  f32x16 accP = (f32x16){}, accS = (f32x16){};

  float4 vregf[4];       // V slab as f32: 4x (row, 4-col granule)
  uint4 breg, creg;
  float4 areg[2];

#define PREF(sx) do {                                                          \
    _Pragma("unroll")                                                          \
    for (int it = 0; it < 4; ++it) {                                           \
      int flat = it * 1024 + tid;                                              \
      int row = flat >> 5, c4 = flat & 31;                                     \
      vregf[it] = *(const float4*)(inputs + (size_t)(m * 128 + row) * D + (sx) * 128 + c4 * 4); \
    }                                                                          \
    _Pragma("unroll")                                                          \
    for (int it = 0; it < 2; ++it) {                                           \
      int flat = it * 1024 + tid;                                              \
      int row = flat >> 4, c = flat & 15;                                      \
      if (it == 0) {                                                           \
        breg = *(const uint4*)(base + ((size_t)m * K + row) * D + (sx) * 128 + c * 8); \
        const float* ap = aux + ((size_t)g * K + row) * D + (sx) * 128 + c * 8; \
        areg[0] = *(const float4*)ap;                                          \
        areg[1] = *(const float4*)(ap + 4);                                    \
      } else {                                                                 \
        creg = *(const uint4*)(cavgb + (size_t)(row - 64) * D + (sx) * 128 + c * 8); \
      }                                                                        \
    }                                                                          \
  } while (0)

#define WRITEB(pb) do {                                                        \
    unsigned short* Vt_ = smem + (pb) * BUFW;                                  \
    unsigned short* Bt_ = Vt_ + 128 * LDV2;                                    \
    _Pragma("unroll")                                                          \
    for (int it = 0; it < 4; ++it) {                                           \
      int flat = it * 1024 + tid;                                              \
      int row = flat >> 5, c4 = flat & 31;                                     \
      ushort4 o;                                                               \
      o.x = f2bf(vregf[it].x); o.y = f2bf(vregf[it].y);                        \
      o.z = f2bf(vregf[it].z); o.w = f2bf(vregf[it].w);                        \
      *(ushort4*)(Vt_ + row * LDV2 + c4 * 4) = o;                              \
    }                                                                          \
    _Pragma("unroll")                                                          \
    for (int it = 0; it < 2; ++it) {                                           \
      int flat = it * 1024 + tid;                                              \
      int row = flat >> 4, c = flat & 15;                                      \
      if (it == 0) {                                                           \
        uint4 ub = breg;                                                       \
        float4 af0 = areg[0], af1 = areg[1];                                   \
        float f0 = bflo(ub.x) + af0.x, f1 = bfhi(ub.x) + af0.y;                \
        float f2 = bflo(ub.y) + af0.z, f3 = bfhi(ub.y) + af0.w;                \
        float f4 = bflo(ub.z) + af1.x, f5 = bfhi(ub.z) + af1.y;                \
        float f6 = bflo(ub.w) + af1.z, f7 = bfhi(ub.w) + af1.w;                \
        float sq = f0*f0 + f1*f1 + f2*f2 + f3*f3 + f4*f4 + f5*f5 + f6*f6 + f7*f7; \
        sq += __shfl_xor(sq, 1); sq += __shfl_xor(sq, 2);                      \
        sq += __shfl_xor(sq, 4); sq += __shfl_xor(sq, 8);                      \
        if ((l & 15) == 0) atomicAdd(&bn2L[row], sq);                          \
        uint4 u;                                                               \
        u.x = (unsigned)f2bf(f0) | ((unsigned)f2bf(f1) << 16);                 \
        u.y = (unsigned)f2bf(f2) | ((unsigned)f2bf(f3) << 16);                 \
        u.z = (unsigned)f2bf(f4) | ((unsigned)f2bf(f5) << 16);                 \
        u.w = (unsigned)f2bf(f6) | ((unsigned)f2bf(f7) << 16);                 \
        *(uint4*)(Bt_ + row * LDV2 + c * 8) = u;                               \
      } else {                                                                 \
        *(uint4*)(Bt_ + row * LDV2 + c * 8) = creg;                            \
      }                                                                        \
    }                                                                          \
  } while (0)

  PREF(0);
  WRITEB(0);
  PREF(1);
  __syncthreads();

  for (int s = 0; s < 6; ++s) {
    const int pb = s & 1;
    if (s < 5) WRITEB(pb ^ 1);     // write next slab (buffer free since barrier)
    if (s < 4) PREF(s + 2);        // refill regs; lands under MFMAs
    const unsigned short* Vt = smem + pb * BUFW;
    const unsigned short* Bt = Vt + 128 * LDV2;
#pragma unroll
    for (int kk = 0; kk < 8; ++kk) {
      bf16x8 av = *(const bf16x8*)(Vt + (32 * wr + r31) * LDV2 + kk * 16 + kh * 8);
      bf16x8 bB = *(const bf16x8*)(Bt + (32 * wc + r31) * LDV2 + kk * 16 + kh * 8);
      accP = __builtin_amdgcn_mfma_f32_32x32x16_bf16(av, bB, accP, 0, 0, 0);
      if (wc <= wr) {   // strict-lower + diag tiles only (upper fully masked)
        bf16x8 bV = *(const bf16x8*)(Vt + (32 * wc + r31) * LDV2 + kk * 16 + kh * 8);
        accS = __builtin_amdgcn_mfma_f32_32x32x16_bf16(av, bV, accS, 0, 0, 0);
      }
    }
    __syncthreads();
  }
#undef PREF
#undef WRITEB

  // ---- pv from Gram diagonal (diag tiles: wr==wc) ----
  if (wr == wc && ((r31 >> 2) & 1) == kh) {
    int q = (r31 & 3) + 4 * (r31 >> 3);
    pvL[32 * wr + r31] = accS[q];
  }

  // ---- masked S -> bf16 into buf0.Vt; one-hot Mt into buf0.Bt ----
  {
    unsigned short* Vt = smem;
    unsigned short* Bt = smem + 128 * LDV2;
#pragma unroll
    for (int q = 0; q < 16; ++q) {
      int i = 32 * wr + (q & 3) + 8 * (q >> 2) + 4 * kh;
      int j = 32 * wc + r31;
      Vt[i * LDV2 + j] = (j < i) ? f2bf(accS[q]) : (unsigned short)0;
    }
    int j = tid & 127;
    int lab = labL[j];
    int kb = (tid >> 7) * 8;
#pragma unroll
    for (int kk = 0; kk < 8; ++kk) {
      int k = kb + kk;
      Bt[k * LDV2 + j] = (lab == k) ? (unsigned short)0x3F80 : (unsigned short)0;
    }
  }
  __syncthreads();

  // ---- corr = tril_strict(S) @ onehot; waves 0-7 own the class-col tiles ----
  if (w < 8) {
    const unsigned short* Vt = smem;
    const unsigned short* Bt = smem + 128 * LDV2;
#pragma unroll
    for (int kk = 0; kk < 8; ++kk) {
      bf16x8 aS = *(const bf16x8*)(Vt + (32 * wr + r31) * LDV2 + kk * 16 + kh * 8);
      bf16x8 bM = *(const bf16x8*)(Bt + (32 * wc + r31) * LDV2 + kk * 16 + kh * 8);
      accP = __builtin_amdgcn_mfma_f32_32x32x16_bf16(aS, bM, accP, 0, 0, 0);
    }
  }
  __syncthreads();

  // ---- dot matrix -> LDS ----
  float* dotL = (float*)smem;
#pragma unroll
  for (int q = 0; q < 16; ++q) {
    int i = 32 * wr + (q & 3) + 8 * (q >> 2) + 4 * kh;
    dotL[i * LDD + 32 * wc + r31] = accP[q];
  }
  __syncthreads();

  // ---- parallel segment summaries: wave w owns rows [8w, 8w+8), lane = class ----
  {
    int k = l;
    float A = 0.f, Fv = 0.f, Pv = 0.f;
    int has = 0;
    int jb = w * 8;
    for (int j = jb; j < jb + 8; ++j) {
      if (labL[j] == k) {
        float t = 2.f * dotL[j * LDD + k] + pvL[j];
        A += t;
        if (!has) { Fv = t; Pv = pvL[j]; has = 1; }
      }
    }
    segA[w][k] = A; segF[w][k] = Fv; segP[w][k] = Pv; segH[w][k] = has;
  }
  __syncthreads();

  // ---- fold prior segments, then emit 8-row segment ----
  {
    int k = l;
    bool seen = cnts_t[k * NCF + m] > 0;
    float n = seen ? bn2L[k] : 0.f;
    for (int ww = 0; ww < w; ++ww) {
      if (segH[ww][k]) {
        n = seen ? (n + segA[ww][k])
                 : (segP[ww][k] + segA[ww][k] - segF[ww][k]);
        seen = true;
      }
    }
    float cnk = cn2[k];
    int jb = w * 8;
    for (int j = jb; j < jb + 8; ++j) {
      float dS = dotL[j * LDD + k];
      float dC = dotL[j * LDD + 64 + k];
      float pvj = pvL[j];
      int lab = labL[j];
      float val = seen ? dS : dC;
      float nn  = seen ? n : cnk;
      out[(size_t)(m * 128 + j) * K + k] = val * rsqrtf(fmaxf(nn * pvj, 1e-30f));
      if (lab == k) {
        n = seen ? (n + 2.f * dS + pvj) : pvj;
        seen = true;
      }
    }
  }
}

// =====================================================================
// FALLBACK PATH — round-1 pipeline, verbatim (known-correct)
// =====================================================================
__global__ __launch_bounds__(256) void ph1_chunk_sums(
    const float* __restrict__ inputs, const int* __restrict__ labels,
    float* __restrict__ sums, int* __restrict__ cnts, int NC, int C)
{
  __shared__ float acc[4 * K * 64];
  __shared__ int   hist[4 * K];
  const int bi    = blockIdx.x;
  const int chunk = bi / 12, slice = bi % 12;
  const int w = threadIdx.x >> 6, l = threadIdx.x & 63;

  for (int e = threadIdx.x; e < 4 * K * 64; e += 256) acc[e] = 0.f;
  hist[threadIdx.x] = 0;
  __syncthreads();

  const int C4 = C >> 2;
  const long long rbase = (long long)chunk * C + (long long)w * C4;
  float* accw = acc + w * (K * 64);
  for (int j = 0; j < C4; ++j) {
    long long r = rbase + j;
    int lab = labels[r];
    float v = inputs[r * D + slice * 64 + l];
    accw[lab * 64 + l] += v;
    if (slice == 0 && l == 0) hist[w * K + lab]++;
  }
  __syncthreads();

  float* sp = sums + (long long)chunk * (K * D) + slice * 64;
  for (int e = threadIdx.x; e < K * 64; e += 256) {
    int k = e >> 6, dl = e & 63;
    float s = acc[0*K*64 + e] + acc[1*K*64 + e] + acc[2*K*64 + e] + acc[3*K*64 + e];
    sp[k * D + dl] = s;
  }
  if (slice == 0 && threadIdx.x < K) {
    cnts[chunk * K + threadIdx.x] =
        hist[0*K + threadIdx.x] + hist[1*K + threadIdx.x] +
        hist[2*K + threadIdx.x] + hist[3*K + threadIdx.x];
  }
}

__global__ __launch_bounds__(256) void ph2a_scan_sums(float* __restrict__ sums, int NC)
{
  const int tid = blockIdx.x * 256 + threadIdx.x;
  float run = 0.f;
  for (int m = 0; m < NC; ++m) {
    long long idx = (long long)m * (K * D) + tid;
    float t = sums[idx];
    sums[idx] = run;
    run += t;
  }
}

__global__ void ph2b_scan_cnts(int* __restrict__ cnts, int NC)
{
  const int k = threadIdx.x;
  int run = 0;
  for (int m = 0; m < NC; ++m) {
    int t = cnts[m * K + k];
    cnts[m * K + k] = run;
    run += t;
  }
}

__global__ __launch_bounds__(256, 4) void ph3_scan(
    const float* __restrict__ inputs, const int* __restrict__ labels,
    const float* __restrict__ cavg, const float* __restrict__ base,
    const int* __restrict__ cnts, float* __restrict__ out, int NC, int C)
{
  const int bi = blockIdx.x;
  int chunk, quad;
  if (NC >= 8) {
    int xcd = bi & 7, slot = bi >> 3;
    chunk = xcd * (NC >> 3) + (slot >> 2);
    quad  = slot & 3;
  } else {
    chunk = bi >> 2; quad = bi & 3;
  }
  const int w = threadIdx.x >> 6, l = threadIdx.x & 63;
  const int k0 = (quad * 4 + w) * 4;

  const int cb = chunk * K + k0;
  bool vg0 = (cnts[cb+0] == 0), vg1 = (cnts[cb+1] == 0);
  bool vg2 = (cnts[cb+2] == 0), vg3 = (cnts[cb+3] == 0);

  const float4* bp = (const float4*)base + (long long)chunk * (K * D4);
  const float4* cp = (const float4*)cavg;

  float4 A0[3], A1[3], A2[3], A3[3];
#pragma unroll
  for (int t = 0; t < 3; ++t) {
    int o = t * 64 + l;
    A0[t] = vg0 ? cp[(k0+0)*D4 + o] : bp[(k0+0)*D4 + o];
    A1[t] = vg1 ? cp[(k0+1)*D4 + o] : bp[(k0+1)*D4 + o];
    A2[t] = vg2 ? cp[(k0+2)*D4 + o] : bp[(k0+2)*D4 + o];
    A3[t] = vg3 ? cp[(k0+3)*D4 + o] : bp[(k0+3)*D4 + o];
  }
  float n0 = 0.f, n1 = 0.f, n2 = 0.f, n3 = 0.f;
#pragma unroll
  for (int t = 0; t < 3; ++t) {
    n0 += d4f(A0[t], A0[t]); n1 += d4f(A1[t], A1[t]);
    n2 += d4f(A2[t], A2[t]); n3 += d4f(A3[t], A3[t]);
  }
#pragma unroll
  for (int m = 1; m <= 32; m <<= 1) {
    n0 += __shfl_xor(n0, m); n1 += __shfl_xor(n1, m);
    n2 += __shfl_xor(n2, m); n3 += __shfl_xor(n3, m);
  }

  const long long ibase = (long long)chunk * C;
  for (int j = 0; j < C; ++j) {
    const long long i = ibase + j;
    const int lab = labels[i];
    const float4* vp = (const float4*)inputs + i * D4;
    float4 v0 = vp[l], v1 = vp[64 + l], v2 = vp[128 + l];

    float p0 = d4f(A0[0], v0) + d4f(A0[1], v1) + d4f(A0[2], v2);
    float p1 = d4f(A1[0], v0) + d4f(A1[1], v1) + d4f(A1[2], v2);
    float p2 = d4f(A2[0], v0) + d4f(A2[1], v1) + d4f(A2[2], v2);
    float p3 = d4f(A3[0], v0) + d4f(A3[1], v1) + d4f(A3[2], v2);
    float pv = d4f(v0, v0) + d4f(v1, v1) + d4f(v2, v2);
#pragma unroll
    for (int m = 1; m <= 32; m <<= 1) {
      p0 += __shfl_xor(p0, m); p1 += __shfl_xor(p1, m);
      p2 += __shfl_xor(p2, m); p3 += __shfl_xor(p3, m);
      pv += __shfl_xor(pv, m);
    }
    if (l < 4) {
      float ps = (l == 0) ? p0 : (l == 1) ? p1 : (l == 2) ? p2 : p3;
      float ns = (l == 0) ? n0 : (l == 1) ? n1 : (l == 2) ? n2 : n3;
      out[i * K + k0 + l] = ps * rsqrtf(fmaxf(ns * pv, 1e-30f));
    }
#define UPD(idx) do { \
      if (vg##idx) { A##idx[0]=v0; A##idx[1]=v1; A##idx[2]=v2; n##idx = pv; vg##idx = false; } \
      else { A##idx[0]=a4(A##idx[0],v0); A##idx[1]=a4(A##idx[1],v1); A##idx[2]=a4(A##idx[2],v2); \
             n##idx += 2.f * p##idx + pv; } } while (0)
    if      (lab == k0 + 0) UPD(0);
    else if (lab == k0 + 1) UPD(1);
    else if (lab == k0 + 2) UPD(2);
    else if (lab == k0 + 3) UPD(3);
#undef UPD
  }
}

// =====================================================================
extern "C" void kernel_launch(void* const* d_in, const int* in_sizes, int n_in,
                              void* d_out, int out_size, void* d_ws, size_t ws_size,
                              hipStream_t stream)
{
  const float* inputs = (const float*)d_in[0];
  const int*   labels = (const int*)d_in[1];
  const float* cavg   = (const float*)d_in[2];
  float* out = (float*)d_out;
  const int N = in_sizes[1];

  const size_t szSums  = (size_t)NCF * K * D * 2; // 25.2 MB (bf16, scanned in place)
  const size_t szAux   = (size_t)16 * K * D * 4;  // 3.1 MB
  const size_t szCnt   = (size_t)K * NCF * 4;
  const size_t szCavgb = (size_t)K * D * 2;
  const size_t szCn2   = (size_t)K * 4;
  size_t need = szSums + szAux + szCnt + szCavgb + szCn2 + 8 * 256;

  if (N == NF && in_sizes[2] == K * D && ws_size >= need) {
    char* p = (char*)d_ws;
    auto take = [&](size_t b) { char* r = p; p += (b + 255) & ~(size_t)255; return r; };
    unsigned short* sums  = (unsigned short*)take(szSums);
    float*          aux   = (float*)take(szAux);
    int*            cnts  = (int*)take(szCnt);
    unsigned short* cavgb = (unsigned short*)take(szCavgb);
    float*          cn2   = (float*)take(szCn2);

    hipLaunchKernelGGL(k2_v11, dim3(NCF * 12 + 16), dim3(256), 0, stream,
                       inputs, labels, cavg, cavgb, cn2, sums, cnts);
    hipLaunchKernelGGL(k3a_scan_lo, dim3(16 * 96), dim3(256), 0, stream, sums, aux);
    hipLaunchKernelGGL(k3b_plus, dim3(193), dim3(256), 0, stream, aux, cnts);
    hipLaunchKernelGGL(k4_v8, dim3(NCF), dim3(1024), 0, stream,
                       inputs, sums, aux, cavgb, labels, cnts, cn2, out);
    return;
  }

  // ---------------- fallback: round-1 pipeline ----------------
  int NC = 256;
  while (NC > 1) {
    size_t nd = (size_t)NC * K * D * 4 + (size_t)NC * K * 4;
    if (nd <= ws_size && (N % (NC * 4)) == 0) break;
    NC >>= 1;
  }
  const int C = N / NC;
  float* d_sums = (float*)d_ws;
  int*   d_cnts = (int*)((char*)d_ws + (size_t)NC * K * D * 4);

  hipLaunchKernelGGL(ph1_chunk_sums, dim3(NC * 12), dim3(256), 0, stream,
                     inputs, labels, d_sums, d_cnts, NC, C);
  hipLaunchKernelGGL(ph2a_scan_sums, dim3((K * D) / 256), dim3(256), 0, stream,
                     d_sums, NC);
  hipLaunchKernelGGL(ph2b_scan_cnts, dim3(1), dim3(64), 0, stream,
                     d_cnts, NC);
  hipLaunchKernelGGL(ph3_scan, dim3(NC * 4), dim3(256), 0, stream,
                     inputs, labels, cavg, d_sums, d_cnts, out, NC, C);
}